// Round 15
// baseline (751.481 us; speedup 1.0000x reference)
//
#include <hip/hip_runtime.h>
#include <hip/hip_bf16.h>

typedef __hip_bfloat16 bf16;
typedef __attribute__((ext_vector_type(8))) short short8;
typedef __attribute__((ext_vector_type(4))) float f32x4;

__device__ __forceinline__ float b2f(bf16 v) { return __bfloat162float(v); }
__device__ __forceinline__ bf16 f2b(float v) { return __float2bfloat16(v); }
__device__ __forceinline__ short fbits(float v) {
  bf16 h = f2b(v); return *reinterpret_cast<short*>(&h);
}
__device__ __forceinline__ float sb2f(short s) {
  return b2f(*reinterpret_cast<bf16*>(&s));
}
// bijective XCD swizzle (m204): contiguous grid chunk per XCD
__device__ __forceinline__ int xcd_swz(int bid, int nwg) {
  int q = nwg >> 3, r = nwg & 7;
  int xcd = bid & 7, idx = bid >> 3;
  return (xcd < r ? xcd * (q + 1) : r * (q + 1) + (xcd - r) * q) + idx;
}

// ---------------------------------------------------------------------------
// Weight repack: w[co][ci][ky][kx] f32  ->  B-fragment order, hi/lo bf16 split.
// Fragment: lane holds B[k][n] with n = cof*16 + (lane&15), k = (lane>>4)*8+j.
// ---------------------------------------------------------------------------
__global__ __launch_bounds__(256) void repack_k(
    const float* __restrict__ w, short* __restrict__ Wr, int Cin, int Cout)
{
  const int nkc = Cin >> 5, ncof = Cout >> 4;
  const size_t gid = (size_t)blockIdx.x * 256 + threadIdx.x;
  const int lane = gid & 63;
  size_t r = gid >> 6;
  const int tap = r % 9; r /= 9;
  const int kcc = r % nkc; r /= nkc;
  const int cof = r % ncof;
  const int hl = r / ncof;
  const int co = cof * 16 + (lane & 15);
  short8 v;
#pragma unroll
  for (int j = 0; j < 8; ++j) {
    int ci = kcc * 32 + ((lane >> 4) * 8 + j);
    float wv = w[((size_t)co * Cin + ci) * 9 + tap];
    bf16 hi = f2b(wv);
    v[j] = hl ? fbits(wv - b2f(hi)) : *reinterpret_cast<short*>(&hi);
  }
  *reinterpret_cast<short8*>(Wr + gid * 8) = v;
}

// ---------------------------------------------------------------------------
// MFMA implicit-GEMM 3x3 conv. BIG-TILE version: block covers R*CX px
// (R=16 -> 256 px) x 64 cout; each wave FM = R*CX/32 px-fragments x 32 co.
// Rationale: weight fragments are re-read from L2 by every spatial block
// (L2-BW-bound at 292cyc/tap/CU vs 40cyc MFMA); 4x bigger tile => 4x less
// weight traffic per FLOP. Per-acc hi->lo order per tap preserved (bit-exact).
// S=1: conv on the SUBSAMPLED image (subsample-then-pad-conv).
// ---------------------------------------------------------------------------
template<int R, int CX, int S>
__global__ __launch_bounds__(256) void conv_mfma_k(
    const bf16* __restrict__ src, bf16* __restrict__ dst,
    const short8* __restrict__ Wr, const float* __restrict__ bias,
    int Win, int Hout, int Wout, int Cin, int Cout, int XT)
{
  constexpr int ROWS = R + 2;
  constexpr int COLS = CX + 2;
  constexpr int NGR = ROWS * 4 * COLS;          // 16B granules per chunk
  constexpr int FM = (R * CX) / 32;             // px-fragments per wave
  __shared__ short8 a_s[NGR];

  const int b = blockIdx.z, cog = blockIdx.y;
  const int xt = blockIdx.x % XT, yt = blockIdx.x / XT;
  const int x0 = xt * CX, y0 = yt * R;
  const int tid = threadIdx.x, lane = tid & 63, wid = tid >> 6;
  const int wm = wid & 1, wn = wid >> 1;
  const int nkc = Cin >> 5;
  const int ncof = Cout >> 4;
  const int l15 = lane & 15, lg = lane >> 4;

  f32x4 acc[FM][2] = {};

  int arow[FM], acolb[FM];
#pragma unroll
  for (int fm = 0; fm < FM; ++fm) {
    int p = wm * (R * CX / 2) + fm * 16 + l15;
    arow[fm] = p / CX;
    acolb[fm] = p % CX;
  }

  auto bload = [&](int hl, int fn, int kcc, int tap) -> short8 {
    int cof = cog * 4 + wn * 2 + fn;
    return Wr[((((size_t)hl * ncof + cof) * nkc + kcc) * 9 + tap) * 64 + lane];
  };

  short8 bc[2][2], bn_[2][2];
  bc[0][0] = bload(0, 0, 0, 0); bc[0][1] = bload(0, 1, 0, 0);
  bc[1][0] = bload(1, 0, 0, 0); bc[1][1] = bload(1, 1, 0, 0);

  for (int kc = 0; kc < nkc; ++kc) {
    __syncthreads();
    for (int idx = tid; idx < NGR; idx += 256) {
      int g = idx & 3, cix = idx >> 2;
      int col = cix % COLS, row = cix / COLS;
      int sy = y0 + row - 1;
      int sx = x0 + col - 1;
      short8 v = {};
      if (sy >= 0 && sy < Hout && sx >= 0 && sx < Wout) {
        int ry = S ? 2 * sy : sy, rx = S ? 2 * sx : sx;
        v = *reinterpret_cast<const short8*>(
            reinterpret_cast<const short*>(src) +
            (((size_t)b * (S ? 2 * Hout : Hout) + ry) * Win + rx) * Cin +
            kc * 32 + g * 8);
      }
      a_s[(row * 4 + g) * COLS + col] = v;
    }
    __syncthreads();

#pragma unroll
    for (int tap = 0; tap < 9; ++tap) {
      const int dy = tap / 3, dx = tap % 3;
      int nt = tap + 1, nk = kc;
      if (nt == 9) { nt = 0; nk = (kc + 1 < nkc) ? kc + 1 : 0; }
      bn_[0][0] = bload(0, 0, nk, nt); bn_[0][1] = bload(0, 1, nk, nt);
      bn_[1][0] = bload(1, 0, nk, nt); bn_[1][1] = bload(1, 1, nk, nt);
#pragma unroll
      for (int fm = 0; fm < FM; ++fm) {
        short8 a = a_s[((arow[fm] + dy) * 4 + lg) * COLS + acolb[fm] + dx];
        acc[fm][0] = __builtin_amdgcn_mfma_f32_16x16x32_bf16(a, bc[0][0], acc[fm][0], 0, 0, 0);
        acc[fm][0] = __builtin_amdgcn_mfma_f32_16x16x32_bf16(a, bc[1][0], acc[fm][0], 0, 0, 0);
        acc[fm][1] = __builtin_amdgcn_mfma_f32_16x16x32_bf16(a, bc[0][1], acc[fm][1], 0, 0, 0);
        acc[fm][1] = __builtin_amdgcn_mfma_f32_16x16x32_bf16(a, bc[1][1], acc[fm][1], 0, 0, 0);
      }
      bc[0][0] = bn_[0][0]; bc[0][1] = bn_[0][1];
      bc[1][0] = bn_[1][0]; bc[1][1] = bn_[1][1];
    }
  }

#pragma unroll
  for (int fn = 0; fn < 2; ++fn) {
    int co = cog * 64 + wn * 32 + fn * 16 + l15;
    float bs = bias[co];
#pragma unroll
    for (int fm = 0; fm < FM; ++fm) {
#pragma unroll
      for (int j = 0; j < 4; ++j) {
        int p = wm * (R * CX / 2) + fm * 16 + lg * 4 + j;
        int r = p / CX, x = p % CX;
        float v = fmaxf(acc[fm][fn][j] + bs, 0.f);
        dst[((size_t)(b * Hout + y0 + r) * Wout + x0 + x) * Cout + co] = f2b(v);
      }
    }
  }
}

// ---------------------------------------------------------------------------
// conv1a: Cin=2 VALU direct conv. NCHW f32 color (subsample-then-conv),
// NHWC bf16 out, bias+ReLU.
// ---------------------------------------------------------------------------
__global__ __launch_bounds__(256) void conv1a_k(
    const float* __restrict__ src, bf16* __restrict__ dst,
    const float* __restrict__ w, const float* __restrict__ bias)
{
  const int b = blockIdx.z, cog = blockIdx.y;
  const int ty0 = (blockIdx.x / 16) * 16, tx0 = (blockIdx.x % 16) * 16;
  const int tid = threadIdx.x, tx = tid & 15, ty = tid >> 4;

  __shared__ float in_s[2][18][18];
  __shared__ __align__(16) float w_s[2][3][3][16];

  for (int idx = tid; idx < 2 * 324; idx += 256) {
    int ci = idx / 324, r = idx - ci * 324;
    int iy = r / 18, ix = r - iy * 18;
    int gy = ty0 + iy - 1, gx = tx0 + ix - 1;
    float v = 0.f;
    if (gy >= 0 && gy < 256 && gx >= 0 && gx < 256)
      v = src[((size_t)(b * 2 + ci) * 512 + 2 * gy) * 512 + 2 * gx];
    in_s[ci][iy][ix] = v;
  }
  for (int idx = tid; idx < 2 * 144; idx += 256) {
    int co = idx & 15, r = idx >> 4;
    int ci = r / 9, k = r - ci * 9;
    w_s[ci][k / 3][k % 3][co] = w[(size_t)((cog * 16 + co) * 2 + ci) * 9 + k];
  }
  __syncthreads();

  float acc[16];
#pragma unroll
  for (int i = 0; i < 16; ++i) acc[i] = 0.f;
  for (int ci = 0; ci < 2; ++ci)
#pragma unroll
    for (int dy = 0; dy < 3; ++dy)
#pragma unroll
      for (int dx = 0; dx < 3; ++dx) {
        float v = in_s[ci][ty + dy][tx + dx];
        const float4* wv = (const float4*)(&w_s[ci][dy][dx][0]);
        float4 w0 = wv[0], w1 = wv[1], w2 = wv[2], w3 = wv[3];
        acc[0] = fmaf(v, w0.x, acc[0]);   acc[1] = fmaf(v, w0.y, acc[1]);
        acc[2] = fmaf(v, w0.z, acc[2]);   acc[3] = fmaf(v, w0.w, acc[3]);
        acc[4] = fmaf(v, w1.x, acc[4]);   acc[5] = fmaf(v, w1.y, acc[5]);
        acc[6] = fmaf(v, w1.z, acc[6]);   acc[7] = fmaf(v, w1.w, acc[7]);
        acc[8] = fmaf(v, w2.x, acc[8]);   acc[9] = fmaf(v, w2.y, acc[9]);
        acc[10] = fmaf(v, w2.z, acc[10]); acc[11] = fmaf(v, w2.w, acc[11]);
        acc[12] = fmaf(v, w3.x, acc[12]); acc[13] = fmaf(v, w3.y, acc[13]);
        acc[14] = fmaf(v, w3.z, acc[14]); acc[15] = fmaf(v, w3.w, acc[15]);
      }

  const int gy = ty0 + ty, gx = tx0 + tx;
  short8 s0, s1;
#pragma unroll
  for (int j = 0; j < 8; ++j) {
    s0[j] = fbits(fmaxf(acc[j] + bias[cog * 16 + j], 0.f));
    s1[j] = fbits(fmaxf(acc[8 + j] + bias[cog * 16 + 8 + j], 0.f));
  }
  short8* dp = reinterpret_cast<short8*>(
      reinterpret_cast<short*>(dst) + (((size_t)(b * 256 + gy) * 256 + gx) * 64 + cog * 16));
  dp[0] = s0; dp[1] = s1;
}

// ---------------------------------------------------------------------------
// InstanceNorm, 2-level.
// ---------------------------------------------------------------------------
__global__ __launch_bounds__(256) void inorm_stats1_k(
    const bf16* __restrict__ x, float2* __restrict__ part, int HW, int C, int nb)
{
  const int b = blockIdx.z, cg = blockIdx.y, pc = blockIdx.x;
  const int c = threadIdx.x & 63, pg = threadIdx.x >> 6;
  const int chunk = HW / gridDim.x;
  const int p0 = pc * chunk;
  float s = 0.f, ss = 0.f;
  for (int p = p0 + pg; p < p0 + chunk; p += 4) {
    float v = b2f(x[((size_t)b * HW + p) * C + cg * 64 + c]);
    s += v; ss += v * v;
  }
  __shared__ float sh[2][4][64];
  sh[0][pg][c] = s; sh[1][pg][c] = ss;
  __syncthreads();
  if (threadIdx.x < 64) {
    int cc = threadIdx.x;
    float s4 = sh[0][0][cc] + sh[0][1][cc] + sh[0][2][cc] + sh[0][3][cc];
    float q4 = sh[1][0][cc] + sh[1][1][cc] + sh[1][2][cc] + sh[1][3][cc];
    part[((size_t)pc * nb + b) * C + cg * 64 + cc] = make_float2(s4, q4);
  }
}

__global__ __launch_bounds__(256) void inorm_stats2_k(
    const float2* __restrict__ part, float2* __restrict__ stats,
    int HW, int C, int PC, int nb)
{
  const int b = blockIdx.y, cg = blockIdx.x;
  const int c = threadIdx.x & 63, i = threadIdx.x >> 6;
  float s = 0.f, ss = 0.f;
  for (int pc = i; pc < PC; pc += 4) {
    float2 v = part[((size_t)pc * nb + b) * C + cg * 64 + c];
    s += v.x; ss += v.y;
  }
  __shared__ float sh[2][4][64];
  sh[0][i][c] = s; sh[1][i][c] = ss;
  __syncthreads();
  if (threadIdx.x < 64) {
    int cc = threadIdx.x;
    float s4 = sh[0][0][cc] + sh[0][1][cc] + sh[0][2][cc] + sh[0][3][cc];
    float q4 = sh[1][0][cc] + sh[1][1][cc] + sh[1][2][cc] + sh[1][3][cc];
    float m = s4 / (float)HW;
    float var = q4 / (float)HW - m * m;
    stats[(size_t)b * C + cg * 64 + cc] = make_float2(m, rsqrtf(var + 1e-5f));
  }
}

// generic apply: NHWC bf16 -> {NHWC bf16, NCHW f32} dests
__global__ __launch_bounds__(256) void inorm_apply_k(
    const bf16* __restrict__ x, const float2* __restrict__ stats, int HW, int C,
    bf16* __restrict__ dnhwc, float* __restrict__ fnchw)
{
  const int b = blockIdx.z, cg = blockIdx.y;
  const int c = cg * 64 + (threadIdx.x & 63);
  const int p = blockIdx.x * 4 + (threadIdx.x >> 6);
  const float2 st = stats[(size_t)b * C + c];
  const size_t ia = ((size_t)b * HW + p) * C + c;
  const float v = (b2f(x[ia]) - st.x) * st.y;
  if (dnhwc) dnhwc[ia] = f2b(v);
  if (fnchw) fnchw[((size_t)(b * C + c)) * HW + p] = v;
}

// ---------------------------------------------------------------------------
// Stage-2 apply: NHWC bf16 -> x-padded NCHW bf16 [b][c][128][144]
// (x at 6+xx, edge-clamped halos). LDS transpose, 16B coalesced writes.
// ---------------------------------------------------------------------------
__global__ __launch_bounds__(256) void inorm_apply_pad_k(
    const bf16* __restrict__ x, const float2* __restrict__ stats,
    bf16* __restrict__ pad)
{
  const int b = blockIdx.z, cg = blockIdx.y, yy = blockIdx.x;
  const int tid = threadIdx.x;
  __shared__ bf16 t_s[64][130];
  __shared__ float2 st_s[64];
  if (tid < 64) st_s[tid] = stats[(size_t)b * 128 + cg * 64 + tid];
  __syncthreads();

  const int c8 = (tid & 7) * 8, px0 = tid >> 3;
#pragma unroll
  for (int pass = 0; pass < 4; ++pass) {
    int px = pass * 32 + px0;
    short8 v = *reinterpret_cast<const short8*>(
        reinterpret_cast<const short*>(x) +
        ((size_t)(b * 16384 + yy * 128 + px) * 128 + cg * 64 + c8));
#pragma unroll
    for (int j = 0; j < 8; ++j) {
      float2 st = st_s[c8 + j];
      t_s[c8 + j][px] = f2b((sb2f(v[j]) - st.x) * st.y);
    }
  }
  __syncthreads();

  for (int idx = tid; idx < 64 * 18; idx += 256) {
    int c = idx / 18, g = idx - (idx / 18) * 18;
    short8 v;
#pragma unroll
    for (int j = 0; j < 8; ++j) {
      int xx = g * 8 + j - 6;
      xx = xx < 0 ? 0 : (xx > 127 ? 127 : xx);
      v[j] = *reinterpret_cast<short*>(&t_s[c][xx]);
    }
    *reinterpret_cast<short8*>(
        reinterpret_cast<short*>(pad) +
        ((size_t)(b * 128 + cg * 64 + c) * 128 + yy) * 144 + g * 8) = v;
  }
}

// ---------------------------------------------------------------------------
// Correlation via MFMA banded GEMM (round-11 version: scatter-built B
// fragments, XCD swizzle, LDS-tile coalesced writes).
// ---------------------------------------------------------------------------
__global__ __launch_bounds__(256) void corr_mfma_k(
    const float* __restrict__ corr, const bf16* __restrict__ pad,
    float* __restrict__ outc, bf16* __restrict__ outn)
{
  __shared__ __align__(16) char smem[26 * 64 * 16];   // 26.6 KB
  short8* a_lds = reinterpret_cast<short8*>(smem);     // [hl*13+dy][lane]
  float* out_s = reinterpret_cast<float*>(smem);       // reused: [16px][132ch]

  const int b = blockIdx.z;
  const int wg = xcd_swz(blockIdx.x, gridDim.x);
  const int y = wg >> 3, xt = wg & 7;
  const int x0 = xt * 16;
  const int tid = threadIdx.x, lane = tid & 63, wid = tid >> 6;
  const int l15 = lane & 15, lg = lane >> 4;

  for (int idx = tid; idx < 26 * 64; idx += 256) {
    short8 z = {};
    a_lds[idx] = z;
  }
  __syncthreads();

  unsigned short* ah = reinterpret_cast<unsigned short*>(a_lds);
  for (int idx = tid; idx < 169 * 16; idx += 256) {
    int t = idx >> 4, m = idx & 15;        // t = dy*13+dx
    int dy = t / 13, dx = t - dy * 13;
    float f = corr[((size_t)b * 169 + t) * 16384 + y * 128 + x0 + m];
    bf16 hi = f2b(f);
    unsigned short hb = *reinterpret_cast<unsigned short*>(&hi);
    unsigned short lb = (unsigned short)fbits(f - b2f(hi));
    int k = m + dx;                        // k in [0,28)
    int ent = dy * 64 + (k >> 3) * 16 + m;
    ah[ent * 8 + (k & 7)] = hb;
    ah[(13 * 64 + ent) * 8 + (k & 7)] = lb;
  }
  __syncthreads();

  const int cg0 = wid * 2;                 // wave: ch [cg0*16, cg0*16+32)
  f32x4 acc0 = {}, acc1 = {};
  const short* pb = reinterpret_cast<const short*>(pad);

  for (int dy = 0; dy < 13; ++dy) {
    int rowc = y + dy - 6; rowc = rowc < 0 ? 0 : (rowc > 127 ? 127 : rowc);
    short8 bhi = a_lds[dy * 64 + lane];
    short8 blo = a_lds[(13 + dy) * 64 + lane];
    size_t base0 = ((size_t)(b * 128 + cg0 * 16 + l15) * 128 + rowc) * 144
                   + x0 + lg * 8;
    short8 a0 = *reinterpret_cast<const short8*>(pb + base0);
    short8 a1 = *reinterpret_cast<const short8*>(pb + base0 + (size_t)16 * 128 * 144);
    acc0 = __builtin_amdgcn_mfma_f32_16x16x32_bf16(a0, bhi, acc0, 0, 0, 0);
    acc1 = __builtin_amdgcn_mfma_f32_16x16x32_bf16(a1, bhi, acc1, 0, 0, 0);
    acc0 = __builtin_amdgcn_mfma_f32_16x16x32_bf16(a0, blo, acc0, 0, 0, 0);
    acc1 = __builtin_amdgcn_mfma_f32_16x16x32_bf16(a1, blo, acc1, 0, 0, 0);
  }
  __syncthreads();                         // a_lds reads done; reuse smem

  // acc -> out_s[px][ch] (f32, stride 132)
#pragma unroll
  for (int cgi = 0; cgi < 2; ++cgi) {
    f32x4 a = cgi ? acc1 : acc0;
    float* dst4 = out_s + l15 * 132 + (cg0 + cgi) * 16 + lg * 4;
    *reinterpret_cast<f32x4*>(dst4) = a;
  }
  __syncthreads();

  // outn: thread = (px, c8): 16B coalesced NHWC rows
  {
    int px_ = tid >> 4, c8 = (tid & 15) * 8;
    const float* row = out_s + px_ * 132 + c8;
    short8 v;
#pragma unroll
    for (int j = 0; j < 8; ++j) v[j] = fbits(row[j]);
    *reinterpret_cast<short8*>(
        reinterpret_cast<short*>(outn) +
        ((size_t)(b * 16384 + y * 128 + x0 + px_)) * 128 + c8) = v;
  }
  // outc: thread = (ch, 8-px half): two float4 stores
  {
    int ch = tid >> 1, pg = tid & 1;
    float v0[4], v1[4];
#pragma unroll
    for (int i = 0; i < 4; ++i) v0[i] = out_s[(pg * 8 + i) * 132 + ch];
#pragma unroll
    for (int i = 0; i < 4; ++i) v1[i] = out_s[(pg * 8 + 4 + i) * 132 + ch];
    float* dst = outc + ((size_t)(b * 128 + ch)) * 16384 + y * 128 + x0 + pg * 8;
    *reinterpret_cast<float4*>(dst) = make_float4(v0[0], v0[1], v0[2], v0[3]);
    *reinterpret_cast<float4*>(dst + 4) = make_float4(v1[0], v1[1], v1[2], v1[3]);
  }
}

// ---------------------------------------------------------------------------
// Workspace plan — BYTES, liveness-proven (round-5/6 table). Peak 62.9 MB.
// ---------------------------------------------------------------------------
extern "C" void kernel_launch(void* const* d_in, const int* in_sizes, int n_in,
                              void* d_out, int out_size, void* d_ws, size_t ws_size,
                              hipStream_t stream) {
  const float* color = (const float*)d_in[0];
  const float* corr  = (const float*)d_in[1];
  const float* w1a = (const float*)d_in[2];  const float* b1a = (const float*)d_in[3];
  const float* w1b = (const float*)d_in[4];  const float* b1b = (const float*)d_in[5];
  const float* w2a = (const float*)d_in[6];  const float* b2a = (const float*)d_in[7];
  const float* w2b = (const float*)d_in[8];  const float* b2b = (const float*)d_in[9];
  const float* w3a = (const float*)d_in[10]; const float* b3a = (const float*)d_in[11];
  const float* w3b = (const float*)d_in[12]; const float* b3b = (const float*)d_in[13];
  const float* w4a = (const float*)d_in[14]; const float* b4a = (const float*)d_in[15];
  const float* w4b = (const float*)d_in[16]; const float* b4b = (const float*)d_in[17];

  float* out = (float*)d_out;
  char* ws = (char*)d_ws;
  const size_t MB = 1048576;
  float2* stats = (float2*)ws;
  float2* part  = (float2*)(ws + (64 << 10));
  short*  WrS   = (short*)(ws + (256 << 10));
  const short8* Wr = (const short8*)WrS;
  bf16* P0 = (bf16*)(ws + 10 * MB);
  bf16* P1 = (bf16*)(ws + 27 * MB);
  bf16* P2 = (bf16*)(ws + 44 * MB);
  bf16* X1 = P0;
  bf16* X2 = (bf16*)d_out;

  // ---- stage 1 ----
  conv1a_k<<<dim3(256, 4, 4), 256, 0, stream>>>(color, X1, w1a, b1a);
  repack_k<<<36, 256, 0, stream>>>(w1b, WrS, 64, 64);
  conv_mfma_k<16, 16, 0><<<dim3(256, 1, 4), 256, 0, stream>>>(
      X1, X2, Wr, b1b, 256, 256, 256, 64, 64, 16);
  inorm_stats1_k<<<dim3(64, 1, 4), 256, 0, stream>>>(X2, part, 65536, 64, 4);
  inorm_stats2_k<<<dim3(1, 4), 256, 0, stream>>>(part, stats, 65536, 64, 64, 4);
  inorm_apply_k<<<dim3(16384, 1, 4), 256, 0, stream>>>(
      X2, stats, 65536, 64, X2, (float*)nullptr);

  // ---- stage 2 ----
  repack_k<<<72, 256, 0, stream>>>(w2a, WrS, 64, 128);
  conv_mfma_k<16, 16, 1><<<dim3(64, 2, 4), 256, 0, stream>>>(
      X2, P0, Wr, b2a, 256, 128, 128, 64, 128, 8);
  repack_k<<<144, 256, 0, stream>>>(w2b, WrS, 128, 128);
  conv_mfma_k<16, 16, 0><<<dim3(64, 2, 4), 256, 0, stream>>>(
      P0, P1, Wr, b2b, 128, 128, 128, 128, 128, 8);
  inorm_stats1_k<<<dim3(16, 2, 4), 256, 0, stream>>>(P1, part, 16384, 128, 4);
  inorm_stats2_k<<<dim3(2, 4), 256, 0, stream>>>(part, stats, 16384, 128, 16, 4);
  inorm_apply_pad_k<<<dim3(128, 2, 4), 256, 0, stream>>>(P1, stats, P2);

  // ---- correlation (MFMA): align_1 -> d_out f32 + P0 NHWC ----
  corr_mfma_k<<<dim3(128 * 8, 1, 4), 256, 0, stream>>>(corr, P2, out, P0);

  // ---- stage 3 ----
  repack_k<<<288, 256, 0, stream>>>(w3a, WrS, 128, 256);
  conv_mfma_k<16, 16, 1><<<dim3(16, 4, 4), 256, 0, stream>>>(
      P0, P1, Wr, b3a, 128, 64, 64, 128, 256, 4);
  repack_k<<<576, 256, 0, stream>>>(w3b, WrS, 256, 256);
  conv_mfma_k<16, 16, 0><<<dim3(16, 4, 4), 256, 0, stream>>>(
      P1, P2, Wr, b3b, 64, 64, 64, 256, 256, 4);
  inorm_stats1_k<<<dim3(4, 4, 4), 256, 0, stream>>>(P2, part, 4096, 256, 4);
  inorm_stats2_k<<<dim3(4, 4), 256, 0, stream>>>(part, stats, 4096, 256, 4, 4);
  inorm_apply_k<<<dim3(1024, 4, 4), 256, 0, stream>>>(
      P2, stats, 4096, 256, P0, out + 8388608);

  // ---- stage 4 ----
  repack_k<<<1152, 256, 0, stream>>>(w4a, WrS, 256, 512);
  conv_mfma_k<8, 16, 1><<<dim3(8, 8, 4), 256, 0, stream>>>(
      P0, P1, Wr, b4a, 64, 32, 32, 256, 512, 2);
  repack_k<<<2304, 256, 0, stream>>>(w4b, WrS, 512, 512);
  conv_mfma_k<8, 16, 0><<<dim3(8, 8, 4), 256, 0, stream>>>(
      P1, P2, Wr, b4b, 32, 32, 32, 512, 512, 2);
  inorm_stats1_k<<<dim3(1, 8, 4), 256, 0, stream>>>(P2, part, 1024, 512, 4);
  inorm_stats2_k<<<dim3(8, 4), 256, 0, stream>>>(part, stats, 1024, 512, 1, 4);
  inorm_apply_k<<<dim3(256, 8, 4), 256, 0, stream>>>(
      P2, stats, 1024, 512, (bf16*)nullptr, out + 12582912);
}

// Round 16
// 725.235 us; speedup vs baseline: 1.0362x; 1.0362x over previous
//
#include <hip/hip_runtime.h>
#include <hip/hip_bf16.h>

typedef __hip_bfloat16 bf16;
typedef __attribute__((ext_vector_type(8))) short short8;
typedef __attribute__((ext_vector_type(4))) float f32x4;

__device__ __forceinline__ float b2f(bf16 v) { return __bfloat162float(v); }
__device__ __forceinline__ bf16 f2b(float v) { return __float2bfloat16(v); }
__device__ __forceinline__ short fbits(float v) {
  bf16 h = f2b(v); return *reinterpret_cast<short*>(&h);
}
__device__ __forceinline__ float sb2f(short s) {
  return b2f(*reinterpret_cast<bf16*>(&s));
}
// bijective XCD swizzle (m204): contiguous grid chunk per XCD
__device__ __forceinline__ int xcd_swz(int bid, int nwg) {
  int q = nwg >> 3, r = nwg & 7;
  int xcd = bid & 7, idx = bid >> 3;
  return (xcd < r ? xcd * (q + 1) : r * (q + 1) + (xcd - r) * q) + idx;
}

// ---------------------------------------------------------------------------
// Weight repack: w[co][ci][ky][kx] f32  ->  B-fragment order, hi/lo bf16 split.
// Fragment: lane holds B[k][n] with n = cof*16 + (lane&15), k = (lane>>4)*8+j.
// ---------------------------------------------------------------------------
__global__ __launch_bounds__(256) void repack_k(
    const float* __restrict__ w, short* __restrict__ Wr, int Cin, int Cout)
{
  const int nkc = Cin >> 5, ncof = Cout >> 4;
  const size_t gid = (size_t)blockIdx.x * 256 + threadIdx.x;
  const int lane = gid & 63;
  size_t r = gid >> 6;
  const int tap = r % 9; r /= 9;
  const int kcc = r % nkc; r /= nkc;
  const int cof = r % ncof;
  const int hl = r / ncof;
  const int co = cof * 16 + (lane & 15);
  short8 v;
#pragma unroll
  for (int j = 0; j < 8; ++j) {
    int ci = kcc * 32 + ((lane >> 4) * 8 + j);
    float wv = w[((size_t)co * Cin + ci) * 9 + tap];
    bf16 hi = f2b(wv);
    v[j] = hl ? fbits(wv - b2f(hi)) : *reinterpret_cast<short*>(&hi);
  }
  *reinterpret_cast<short8*>(Wr + gid * 8) = v;
}

// ---------------------------------------------------------------------------
// MFMA implicit-GEMM 3x3 conv (r14 structure: 4x16 tile, T14 stage-split).
// NEW: optional `stats` (per-(b,c) mean/rsqrt) applied during staging —
// bit-exact replacement for a separate inorm-apply pass (zero padding
// remains zero: normalize only inside the bounds check).
// S=1: conv on the SUBSAMPLED image (subsample-then-pad-conv).
// ---------------------------------------------------------------------------
template<int R, int CX, int S>
__global__ __launch_bounds__(256) void conv_mfma_k(
    const bf16* __restrict__ src, bf16* __restrict__ dst,
    const short8* __restrict__ Wr, const float* __restrict__ bias,
    const float2* __restrict__ stats,
    int Win, int Hout, int Wout, int Cin, int Cout, int XT)
{
  constexpr int ROWS = R + 2;
  constexpr int COLS = CX + 2;
  constexpr int NGR = ROWS * 4 * COLS;          // 16B granules per chunk
  __shared__ short8 a_s[NGR];

  const int b = blockIdx.z, cog = blockIdx.y;
  const int xt = blockIdx.x % XT, yt = blockIdx.x / XT;
  const int x0 = xt * CX, y0 = yt * R;
  const int tid = threadIdx.x, lane = tid & 63, wid = tid >> 6;
  const int wm = wid & 1, wn = wid >> 1;
  const int nkc = Cin >> 5;
  const int ncof = Cout >> 4;
  const int l15 = lane & 15, lg = lane >> 4;

  f32x4 acc[2][2] = {};

  int arow[2], acolb[2];
#pragma unroll
  for (int fm = 0; fm < 2; ++fm) {
    int p = wm * 32 + fm * 16 + l15;
    arow[fm] = p / CX;
    acolb[fm] = p % CX;
  }

  auto bload = [&](int hl, int fn, int kcc, int tap) -> short8 {
    int cof = cog * 4 + wn * 2 + fn;
    return Wr[((((size_t)hl * ncof + cof) * nkc + kcc) * 9 + tap) * 64 + lane];
  };
  // value of 16B A-granule idx of chunk kcc (idx = (row*COLS+col)*4 + g)
  auto gload = [&](int kcc, int idx) -> short8 {
    int g = idx & 3, cix = idx >> 2;
    int col = cix % COLS, row = cix / COLS;
    int sy = y0 + row - 1;
    int sx = x0 + col - 1;
    short8 v = {};
    if (sy >= 0 && sy < Hout && sx >= 0 && sx < Wout) {
      int ry = S ? 2 * sy : sy, rx = S ? 2 * sx : sx;
      v = *reinterpret_cast<const short8*>(
          reinterpret_cast<const short*>(src) +
          (((size_t)b * (S ? 2 * Hout : Hout) + ry) * Win + rx) * Cin +
          kcc * 32 + g * 8);
      if (stats) {                       // fused inorm apply (bit-exact)
        const float2* st = stats + (size_t)b * Cin + kcc * 32 + g * 8;
#pragma unroll
        for (int j = 0; j < 8; ++j)
          v[j] = fbits((sb2f(v[j]) - st[j].x) * st[j].y);
      }
    }
    return v;
  };
  // LDS slot for granule idx — matches fragment-read layout
  auto slot_of = [&](int idx) -> int {
    int g = idx & 3, cix = idx >> 2;
    int col = cix % COLS, row = cix / COLS;
    return (row * 4 + g) * COLS + col;
  };

  short8 bc00 = bload(0, 0, 0, 0), bc01 = bload(0, 1, 0, 0);
  short8 bc10 = bload(1, 0, 0, 0), bc11 = bload(1, 1, 0, 0);

  // prologue: stage chunk 0
  {
    short8 s0 = {}, s1 = {};
    if (tid < NGR) s0 = gload(0, tid);
    if (tid + 256 < NGR) s1 = gload(0, tid + 256);
    if (tid < NGR) a_s[slot_of(tid)] = s0;
    if (tid + 256 < NGR) a_s[slot_of(tid + 256)] = s1;
  }
  __syncthreads();

  for (int kc = 0; kc < nkc; ++kc) {
    short8 s0 = {}, s1 = {};
    const bool more = (kc + 1 < nkc);
    if (more) {
      if (tid < NGR) s0 = gload(kc + 1, tid);
      if (tid + 256 < NGR) s1 = gload(kc + 1, tid + 256);
    }

#pragma unroll
    for (int tap = 0; tap < 9; ++tap) {
      const int dy = tap / 3, dx = tap % 3;
      int nt = tap + 1, nk = kc;
      if (nt == 9) { nt = 0; nk = (kc + 1 < nkc) ? kc + 1 : 0; }
      short8 bn00 = bload(0, 0, nk, nt), bn01 = bload(0, 1, nk, nt);
      short8 bn10 = bload(1, 0, nk, nt), bn11 = bload(1, 1, nk, nt);
      short8 a0 = a_s[((arow[0] + dy) * 4 + lg) * COLS + acolb[0] + dx];
      short8 a1 = a_s[((arow[1] + dy) * 4 + lg) * COLS + acolb[1] + dx];
      acc[0][0] = __builtin_amdgcn_mfma_f32_16x16x32_bf16(a0, bc00, acc[0][0], 0, 0, 0);
      acc[0][0] = __builtin_amdgcn_mfma_f32_16x16x32_bf16(a0, bc10, acc[0][0], 0, 0, 0);
      acc[0][1] = __builtin_amdgcn_mfma_f32_16x16x32_bf16(a0, bc01, acc[0][1], 0, 0, 0);
      acc[0][1] = __builtin_amdgcn_mfma_f32_16x16x32_bf16(a0, bc11, acc[0][1], 0, 0, 0);
      acc[1][0] = __builtin_amdgcn_mfma_f32_16x16x32_bf16(a1, bc00, acc[1][0], 0, 0, 0);
      acc[1][0] = __builtin_amdgcn_mfma_f32_16x16x32_bf16(a1, bc10, acc[1][0], 0, 0, 0);
      acc[1][1] = __builtin_amdgcn_mfma_f32_16x16x32_bf16(a1, bc01, acc[1][1], 0, 0, 0);
      acc[1][1] = __builtin_amdgcn_mfma_f32_16x16x32_bf16(a1, bc11, acc[1][1], 0, 0, 0);
      bc00 = bn00; bc01 = bn01; bc10 = bn10; bc11 = bn11;
    }

    if (more) {
      __syncthreads();
      if (tid < NGR) a_s[slot_of(tid)] = s0;
      if (tid + 256 < NGR) a_s[slot_of(tid + 256)] = s1;
      __syncthreads();
    }
  }

#pragma unroll
  for (int fn = 0; fn < 2; ++fn) {
    int co = cog * 64 + wn * 32 + fn * 16 + l15;
    float bs = bias[co];
#pragma unroll
    for (int fm = 0; fm < 2; ++fm) {
#pragma unroll
      for (int j = 0; j < 4; ++j) {
        int p = wm * 32 + fm * 16 + lg * 4 + j;
        int r = p / CX, x = p % CX;
        float v = fmaxf(acc[fm][fn][j] + bs, 0.f);
        dst[((size_t)(b * Hout + y0 + r) * Wout + x0 + x) * Cout + co] = f2b(v);
      }
    }
  }
}

// ---------------------------------------------------------------------------
// conv1a: Cin=2 VALU direct conv. NCHW f32 color (subsample-then-conv),
// NHWC bf16 out, bias+ReLU.
// ---------------------------------------------------------------------------
__global__ __launch_bounds__(256) void conv1a_k(
    const float* __restrict__ src, bf16* __restrict__ dst,
    const float* __restrict__ w, const float* __restrict__ bias)
{
  const int b = blockIdx.z, cog = blockIdx.y;
  const int ty0 = (blockIdx.x / 16) * 16, tx0 = (blockIdx.x % 16) * 16;
  const int tid = threadIdx.x, tx = tid & 15, ty = tid >> 4;

  __shared__ float in_s[2][18][18];
  __shared__ __align__(16) float w_s[2][3][3][16];

  for (int idx = tid; idx < 2 * 324; idx += 256) {
    int ci = idx / 324, r = idx - ci * 324;
    int iy = r / 18, ix = r - iy * 18;
    int gy = ty0 + iy - 1, gx = tx0 + ix - 1;
    float v = 0.f;
    if (gy >= 0 && gy < 256 && gx >= 0 && gx < 256)
      v = src[((size_t)(b * 2 + ci) * 512 + 2 * gy) * 512 + 2 * gx];
    in_s[ci][iy][ix] = v;
  }
  for (int idx = tid; idx < 2 * 144; idx += 256) {
    int co = idx & 15, r = idx >> 4;
    int ci = r / 9, k = r - ci * 9;
    w_s[ci][k / 3][k % 3][co] = w[(size_t)((cog * 16 + co) * 2 + ci) * 9 + k];
  }
  __syncthreads();

  float acc[16];
#pragma unroll
  for (int i = 0; i < 16; ++i) acc[i] = 0.f;
  for (int ci = 0; ci < 2; ++ci)
#pragma unroll
    for (int dy = 0; dy < 3; ++dy)
#pragma unroll
      for (int dx = 0; dx < 3; ++dx) {
        float v = in_s[ci][ty + dy][tx + dx];
        const float4* wv = (const float4*)(&w_s[ci][dy][dx][0]);
        float4 w0 = wv[0], w1 = wv[1], w2 = wv[2], w3 = wv[3];
        acc[0] = fmaf(v, w0.x, acc[0]);   acc[1] = fmaf(v, w0.y, acc[1]);
        acc[2] = fmaf(v, w0.z, acc[2]);   acc[3] = fmaf(v, w0.w, acc[3]);
        acc[4] = fmaf(v, w1.x, acc[4]);   acc[5] = fmaf(v, w1.y, acc[5]);
        acc[6] = fmaf(v, w1.z, acc[6]);   acc[7] = fmaf(v, w1.w, acc[7]);
        acc[8] = fmaf(v, w2.x, acc[8]);   acc[9] = fmaf(v, w2.y, acc[9]);
        acc[10] = fmaf(v, w2.z, acc[10]); acc[11] = fmaf(v, w2.w, acc[11]);
        acc[12] = fmaf(v, w3.x, acc[12]); acc[13] = fmaf(v, w3.y, acc[13]);
        acc[14] = fmaf(v, w3.z, acc[14]); acc[15] = fmaf(v, w3.w, acc[15]);
      }

  const int gy = ty0 + ty, gx = tx0 + tx;
  short8 s0, s1;
#pragma unroll
  for (int j = 0; j < 8; ++j) {
    s0[j] = fbits(fmaxf(acc[j] + bias[cog * 16 + j], 0.f));
    s1[j] = fbits(fmaxf(acc[8 + j] + bias[cog * 16 + 8 + j], 0.f));
  }
  short8* dp = reinterpret_cast<short8*>(
      reinterpret_cast<short*>(dst) + (((size_t)(b * 256 + gy) * 256 + gx) * 64 + cog * 16));
  dp[0] = s0; dp[1] = s1;
}

// ---------------------------------------------------------------------------
// InstanceNorm, 2-level.
// ---------------------------------------------------------------------------
__global__ __launch_bounds__(256) void inorm_stats1_k(
    const bf16* __restrict__ x, float2* __restrict__ part, int HW, int C, int nb)
{
  const int b = blockIdx.z, cg = blockIdx.y, pc = blockIdx.x;
  const int c = threadIdx.x & 63, pg = threadIdx.x >> 6;
  const int chunk = HW / gridDim.x;
  const int p0 = pc * chunk;
  float s = 0.f, ss = 0.f;
  for (int p = p0 + pg; p < p0 + chunk; p += 4) {
    float v = b2f(x[((size_t)b * HW + p) * C + cg * 64 + c]);
    s += v; ss += v * v;
  }
  __shared__ float sh[2][4][64];
  sh[0][pg][c] = s; sh[1][pg][c] = ss;
  __syncthreads();
  if (threadIdx.x < 64) {
    int cc = threadIdx.x;
    float s4 = sh[0][0][cc] + sh[0][1][cc] + sh[0][2][cc] + sh[0][3][cc];
    float q4 = sh[1][0][cc] + sh[1][1][cc] + sh[1][2][cc] + sh[1][3][cc];
    part[((size_t)pc * nb + b) * C + cg * 64 + cc] = make_float2(s4, q4);
  }
}

__global__ __launch_bounds__(256) void inorm_stats2_k(
    const float2* __restrict__ part, float2* __restrict__ stats,
    int HW, int C, int PC, int nb)
{
  const int b = blockIdx.y, cg = blockIdx.x;
  const int c = threadIdx.x & 63, i = threadIdx.x >> 6;
  float s = 0.f, ss = 0.f;
  for (int pc = i; pc < PC; pc += 4) {
    float2 v = part[((size_t)pc * nb + b) * C + cg * 64 + c];
    s += v.x; ss += v.y;
  }
  __shared__ float sh[2][4][64];
  sh[0][i][c] = s; sh[1][i][c] = ss;
  __syncthreads();
  if (threadIdx.x < 64) {
    int cc = threadIdx.x;
    float s4 = sh[0][0][cc] + sh[0][1][cc] + sh[0][2][cc] + sh[0][3][cc];
    float q4 = sh[1][0][cc] + sh[1][1][cc] + sh[1][2][cc] + sh[1][3][cc];
    float m = s4 / (float)HW;
    float var = q4 / (float)HW - m * m;
    stats[(size_t)b * C + cg * 64 + cc] = make_float2(m, rsqrtf(var + 1e-5f));
  }
}

// generic apply: NHWC bf16 -> {NHWC bf16, NCHW f32} dests
__global__ __launch_bounds__(256) void inorm_apply_k(
    const bf16* __restrict__ x, const float2* __restrict__ stats, int HW, int C,
    bf16* __restrict__ dnhwc, float* __restrict__ fnchw)
{
  const int b = blockIdx.z, cg = blockIdx.y;
  const int c = cg * 64 + (threadIdx.x & 63);
  const int p = blockIdx.x * 4 + (threadIdx.x >> 6);
  const float2 st = stats[(size_t)b * C + c];
  const size_t ia = ((size_t)b * HW + p) * C + c;
  const float v = (b2f(x[ia]) - st.x) * st.y;
  if (dnhwc) dnhwc[ia] = f2b(v);
  if (fnchw) fnchw[((size_t)(b * C + c)) * HW + p] = v;
}

// ---------------------------------------------------------------------------
// Stage-2 apply: NHWC bf16 -> x-padded NCHW bf16 [b][c][128][144]
// (x at 6+xx, edge-clamped halos). LDS transpose, 16B coalesced writes.
// ---------------------------------------------------------------------------
__global__ __launch_bounds__(256) void inorm_apply_pad_k(
    const bf16* __restrict__ x, const float2* __restrict__ stats,
    bf16* __restrict__ pad)
{
  const int b = blockIdx.z, cg = blockIdx.y, yy = blockIdx.x;
  const int tid = threadIdx.x;
  __shared__ bf16 t_s[64][130];
  __shared__ float2 st_s[64];
  if (tid < 64) st_s[tid] = stats[(size_t)b * 128 + cg * 64 + tid];
  __syncthreads();

  const int c8 = (tid & 7) * 8, px0 = tid >> 3;
#pragma unroll
  for (int pass = 0; pass < 4; ++pass) {
    int px = pass * 32 + px0;
    short8 v = *reinterpret_cast<const short8*>(
        reinterpret_cast<const short*>(x) +
        ((size_t)(b * 16384 + yy * 128 + px) * 128 + cg * 64 + c8));
#pragma unroll
    for (int j = 0; j < 8; ++j) {
      float2 st = st_s[c8 + j];
      t_s[c8 + j][px] = f2b((sb2f(v[j]) - st.x) * st.y);
    }
  }
  __syncthreads();

  for (int idx = tid; idx < 64 * 18; idx += 256) {
    int c = idx / 18, g = idx - (idx / 18) * 18;
    short8 v;
#pragma unroll
    for (int j = 0; j < 8; ++j) {
      int xx = g * 8 + j - 6;
      xx = xx < 0 ? 0 : (xx > 127 ? 127 : xx);
      v[j] = *reinterpret_cast<short*>(&t_s[c][xx]);
    }
    *reinterpret_cast<short8*>(
        reinterpret_cast<short*>(pad) +
        ((size_t)(b * 128 + cg * 64 + c) * 128 + yy) * 144 + g * 8) = v;
  }
}

// ---------------------------------------------------------------------------
// Correlation via MFMA banded GEMM (r11 structure). `b0` = batch offset so
// the launch can be split into 2 half-batch dispatches (profiler visibility).
// ---------------------------------------------------------------------------
__global__ __launch_bounds__(256) void corr_mfma_k(
    const float* __restrict__ corr, const bf16* __restrict__ pad,
    float* __restrict__ outc, bf16* __restrict__ outn, int b0)
{
  __shared__ __align__(16) char smem[26 * 64 * 16];   // 26.6 KB
  short8* a_lds = reinterpret_cast<short8*>(smem);     // [hl*13+dy][lane]
  float* out_s = reinterpret_cast<float*>(smem);       // reused: [16px][132ch]

  const int b = b0 + blockIdx.z;
  const int wg = xcd_swz(blockIdx.x, gridDim.x);
  const int y = wg >> 3, xt = wg & 7;
  const int x0 = xt * 16;
  const int tid = threadIdx.x, lane = tid & 63, wid = tid >> 6;
  const int l15 = lane & 15, lg = lane >> 4;

  for (int idx = tid; idx < 26 * 64; idx += 256) {
    short8 z = {};
    a_lds[idx] = z;
  }
  __syncthreads();

  unsigned short* ah = reinterpret_cast<unsigned short*>(a_lds);
  for (int idx = tid; idx < 169 * 16; idx += 256) {
    int t = idx >> 4, m = idx & 15;        // t = dy*13+dx
    int dy = t / 13, dx = t - dy * 13;
    float f = corr[((size_t)b * 169 + t) * 16384 + y * 128 + x0 + m];
    bf16 hi = f2b(f);
    unsigned short hb = *reinterpret_cast<unsigned short*>(&hi);
    unsigned short lb = (unsigned short)fbits(f - b2f(hi));
    int k = m + dx;                        // k in [0,28)
    int ent = dy * 64 + (k >> 3) * 16 + m;
    ah[ent * 8 + (k & 7)] = hb;
    ah[(13 * 64 + ent) * 8 + (k & 7)] = lb;
  }
  __syncthreads();

  const int cg0 = wid * 2;                 // wave: ch [cg0*16, cg0*16+32)
  f32x4 acc0 = {}, acc1 = {};
  const short* pb = reinterpret_cast<const short*>(pad);

  for (int dy = 0; dy < 13; ++dy) {
    int rowc = y + dy - 6; rowc = rowc < 0 ? 0 : (rowc > 127 ? 127 : rowc);
    short8 bhi = a_lds[dy * 64 + lane];
    short8 blo = a_lds[(13 + dy) * 64 + lane];
    size_t base0 = ((size_t)(b * 128 + cg0 * 16 + l15) * 128 + rowc) * 144
                   + x0 + lg * 8;
    short8 a0 = *reinterpret_cast<const short8*>(pb + base0);
    short8 a1 = *reinterpret_cast<const short8*>(pb + base0 + (size_t)16 * 128 * 144);
    acc0 = __builtin_amdgcn_mfma_f32_16x16x32_bf16(a0, bhi, acc0, 0, 0, 0);
    acc1 = __builtin_amdgcn_mfma_f32_16x16x32_bf16(a1, bhi, acc1, 0, 0, 0);
    acc0 = __builtin_amdgcn_mfma_f32_16x16x32_bf16(a0, blo, acc0, 0, 0, 0);
    acc1 = __builtin_amdgcn_mfma_f32_16x16x32_bf16(a1, blo, acc1, 0, 0, 0);
  }
  __syncthreads();                         // a_lds reads done; reuse smem

#pragma unroll
  for (int cgi = 0; cgi < 2; ++cgi) {
    f32x4 a = cgi ? acc1 : acc0;
    float* dst4 = out_s + l15 * 132 + (cg0 + cgi) * 16 + lg * 4;
    *reinterpret_cast<f32x4*>(dst4) = a;
  }
  __syncthreads();

  {
    int px_ = tid >> 4, c8 = (tid & 15) * 8;
    const float* row = out_s + px_ * 132 + c8;
    short8 v;
#pragma unroll
    for (int j = 0; j < 8; ++j) v[j] = fbits(row[j]);
    *reinterpret_cast<short8*>(
        reinterpret_cast<short*>(outn) +
        ((size_t)(b * 16384 + y * 128 + x0 + px_)) * 128 + c8) = v;
  }
  {
    int ch = tid >> 1, pg = tid & 1;
    float v0[4], v1[4];
#pragma unroll
    for (int i = 0; i < 4; ++i) v0[i] = out_s[(pg * 8 + i) * 132 + ch];
#pragma unroll
    for (int i = 0; i < 4; ++i) v1[i] = out_s[(pg * 8 + 4 + i) * 132 + ch];
    float* dst = outc + ((size_t)(b * 128 + ch)) * 16384 + y * 128 + x0 + pg * 8;
    *reinterpret_cast<float4*>(dst) = make_float4(v0[0], v0[1], v0[2], v0[3]);
    *reinterpret_cast<float4*>(dst + 4) = make_float4(v1[0], v1[1], v1[2], v1[3]);
  }
}

// ---------------------------------------------------------------------------
// Workspace plan — BYTES, liveness-proven (round-5/6 table). Peak 62.9 MB.
// ---------------------------------------------------------------------------
extern "C" void kernel_launch(void* const* d_in, const int* in_sizes, int n_in,
                              void* d_out, int out_size, void* d_ws, size_t ws_size,
                              hipStream_t stream) {
  const float* color = (const float*)d_in[0];
  const float* corr  = (const float*)d_in[1];
  const float* w1a = (const float*)d_in[2];  const float* b1a = (const float*)d_in[3];
  const float* w1b = (const float*)d_in[4];  const float* b1b = (const float*)d_in[5];
  const float* w2a = (const float*)d_in[6];  const float* b2a = (const float*)d_in[7];
  const float* w2b = (const float*)d_in[8];  const float* b2b = (const float*)d_in[9];
  const float* w3a = (const float*)d_in[10]; const float* b3a = (const float*)d_in[11];
  const float* w3b = (const float*)d_in[12]; const float* b3b = (const float*)d_in[13];
  const float* w4a = (const float*)d_in[14]; const float* b4a = (const float*)d_in[15];
  const float* w4b = (const float*)d_in[16]; const float* b4b = (const float*)d_in[17];

  float* out = (float*)d_out;
  char* ws = (char*)d_ws;
  const size_t MB = 1048576;
  float2* stats = (float2*)ws;
  float2* part  = (float2*)(ws + (64 << 10));
  short*  WrS   = (short*)(ws + (256 << 10));
  const short8* Wr = (const short8*)WrS;
  bf16* P0 = (bf16*)(ws + 10 * MB);
  bf16* P1 = (bf16*)(ws + 27 * MB);
  bf16* P2 = (bf16*)(ws + 44 * MB);
  bf16* X1 = P0;
  bf16* X2 = (bf16*)d_out;
  const float2* nost = (const float2*)nullptr;

  // ---- stage 1: conv1a -> conv1b -> stats (apply fused into conv2a) ----
  conv1a_k<<<dim3(256, 4, 4), 256, 0, stream>>>(color, X1, w1a, b1a);
  repack_k<<<36, 256, 0, stream>>>(w1b, WrS, 64, 64);
  conv_mfma_k<4, 16, 0><<<dim3(64 * 16, 1, 4), 256, 0, stream>>>(
      X1, X2, Wr, b1b, nost, 256, 256, 256, 64, 64, 16);
  inorm_stats1_k<<<dim3(64, 1, 4), 256, 0, stream>>>(X2, part, 65536, 64, 4);
  inorm_stats2_k<<<dim3(1, 4), 256, 0, stream>>>(part, stats, 65536, 64, 64, 4);

  // ---- stage 2: conv2a (reads raw X2 + stats) -> conv2b -> pad apply ----
  repack_k<<<72, 256, 0, stream>>>(w2a, WrS, 64, 128);
  conv_mfma_k<4, 16, 1><<<dim3(32 * 8, 2, 4), 256, 0, stream>>>(
      X2, P0, Wr, b2a, stats, 256, 128, 128, 64, 128, 8);
  repack_k<<<144, 256, 0, stream>>>(w2b, WrS, 128, 128);
  conv_mfma_k<4, 16, 0><<<dim3(32 * 8, 2, 4), 256, 0, stream>>>(
      P0, P1, Wr, b2b, nost, 128, 128, 128, 128, 128, 8);
  inorm_stats1_k<<<dim3(16, 2, 4), 256, 0, stream>>>(P1, part, 16384, 128, 4);
  inorm_stats2_k<<<dim3(2, 4), 256, 0, stream>>>(part, stats, 16384, 128, 16, 4);
  inorm_apply_pad_k<<<dim3(128, 2, 4), 256, 0, stream>>>(P1, stats, P2);

  // ---- correlation (MFMA), split into 2 half-batch dispatches ----
  corr_mfma_k<<<dim3(128 * 8, 1, 2), 256, 0, stream>>>(corr, P2, out, P0, 0);
  corr_mfma_k<<<dim3(128 * 8, 1, 2), 256, 0, stream>>>(corr, P2, out, P0, 2);

  // ---- stage 3: conv3a -> conv3b -> stats; apply writes f32 only ----
  repack_k<<<288, 256, 0, stream>>>(w3a, WrS, 128, 256);
  conv_mfma_k<4, 16, 1><<<dim3(16 * 4, 4, 4), 256, 0, stream>>>(
      P0, P1, Wr, b3a, nost, 128, 64, 64, 128, 256, 4);
  repack_k<<<576, 256, 0, stream>>>(w3b, WrS, 256, 256);
  conv_mfma_k<4, 16, 0><<<dim3(16 * 4, 4, 4), 256, 0, stream>>>(
      P1, P2, Wr, b3b, nost, 64, 64, 64, 256, 256, 4);
  inorm_stats1_k<<<dim3(4, 4, 4), 256, 0, stream>>>(P2, part, 4096, 256, 4);
  inorm_stats2_k<<<dim3(4, 4), 256, 0, stream>>>(part, stats, 4096, 256, 4, 4);
  inorm_apply_k<<<dim3(1024, 4, 4), 256, 0, stream>>>(
      P2, stats, 4096, 256, (bf16*)nullptr, out + 8388608);

  // ---- stage 4: conv4a (reads raw P2 + stats) -> conv4b -> inorm ----
  repack_k<<<1152, 256, 0, stream>>>(w4a, WrS, 256, 512);
  conv_mfma_k<4, 16, 1><<<dim3(8 * 2, 8, 4), 256, 0, stream>>>(
      P2, P1, Wr, b4a, stats, 64, 32, 32, 256, 512, 2);
  repack_k<<<2304, 256, 0, stream>>>(w4b, WrS, 512, 512);
  conv_mfma_k<4, 16, 0><<<dim3(8 * 2, 8, 4), 256, 0, stream>>>(
      P1, P2, Wr, b4b, nost, 32, 32, 32, 512, 512, 2);
  inorm_stats1_k<<<dim3(1, 8, 4), 256, 0, stream>>>(P2, part, 1024, 512, 4);
  inorm_stats2_k<<<dim3(8, 4), 256, 0, stream>>>(part, stats, 1024, 512, 1, 4);
  inorm_apply_k<<<dim3(256, 8, 4), 256, 0, stream>>>(
      P2, stats, 1024, 512, (bf16*)nullptr, out + 12582912);
}

// Round 17
// 498.145 us; speedup vs baseline: 1.5086x; 1.4559x over previous
//
#include <hip/hip_runtime.h>
#include <hip/hip_bf16.h>

typedef __hip_bfloat16 bf16;
typedef __attribute__((ext_vector_type(8))) short short8;
typedef __attribute__((ext_vector_type(4))) float f32x4;

__device__ __forceinline__ float b2f(bf16 v) { return __bfloat162float(v); }
__device__ __forceinline__ bf16 f2b(float v) { return __float2bfloat16(v); }
__device__ __forceinline__ short fbits(float v) {
  bf16 h = f2b(v); return *reinterpret_cast<short*>(&h);
}
__device__ __forceinline__ float sb2f(short s) {
  return b2f(*reinterpret_cast<bf16*>(&s));
}
// bijective XCD swizzle (m204): contiguous grid chunk per XCD
__device__ __forceinline__ int xcd_swz(int bid, int nwg) {
  int q = nwg >> 3, r = nwg & 7;
  int xcd = bid & 7, idx = bid >> 3;
  return (xcd < r ? xcd * (q + 1) : r * (q + 1) + (xcd - r) * q) + idx;
}

// ---------------------------------------------------------------------------
// Weight repack: w[co][ci][ky][kx] f32  ->  B-fragment order, hi/lo bf16 split.
// ---------------------------------------------------------------------------
__global__ __launch_bounds__(256) void repack_k(
    const float* __restrict__ w, short* __restrict__ Wr, int Cin, int Cout)
{
  const int nkc = Cin >> 5, ncof = Cout >> 4;
  const size_t gid = (size_t)blockIdx.x * 256 + threadIdx.x;
  const int lane = gid & 63;
  size_t r = gid >> 6;
  const int tap = r % 9; r /= 9;
  const int kcc = r % nkc; r /= nkc;
  const int cof = r % ncof;
  const int hl = r / ncof;
  const int co = cof * 16 + (lane & 15);
  short8 v;
#pragma unroll
  for (int j = 0; j < 8; ++j) {
    int ci = kcc * 32 + ((lane >> 4) * 8 + j);
    float wv = w[((size_t)co * Cin + ci) * 9 + tap];
    bf16 hi = f2b(wv);
    v[j] = hl ? fbits(wv - b2f(hi)) : *reinterpret_cast<short*>(&hi);
  }
  *reinterpret_cast<short8*>(Wr + gid * 8) = v;
}

// ---------------------------------------------------------------------------
// MFMA implicit-GEMM 3x3 conv (r14 structure: 4x16 tile, T14 stage-split).
// Optional `stats` applied during staging (bit-exact fused inorm).
// S=1: conv on the SUBSAMPLED image (subsample-then-pad-conv).
// ---------------------------------------------------------------------------
template<int R, int CX, int S>
__global__ __launch_bounds__(256) void conv_mfma_k(
    const bf16* __restrict__ src, bf16* __restrict__ dst,
    const short8* __restrict__ Wr, const float* __restrict__ bias,
    const float2* __restrict__ stats,
    int Win, int Hout, int Wout, int Cin, int Cout, int XT)
{
  constexpr int ROWS = R + 2;
  constexpr int COLS = CX + 2;
  constexpr int NGR = ROWS * 4 * COLS;
  __shared__ short8 a_s[NGR];

  const int b = blockIdx.z, cog = blockIdx.y;
  const int xt = blockIdx.x % XT, yt = blockIdx.x / XT;
  const int x0 = xt * CX, y0 = yt * R;
  const int tid = threadIdx.x, lane = tid & 63, wid = tid >> 6;
  const int wm = wid & 1, wn = wid >> 1;
  const int nkc = Cin >> 5;
  const int ncof = Cout >> 4;
  const int l15 = lane & 15, lg = lane >> 4;

  f32x4 acc[2][2] = {};

  int arow[2], acolb[2];
#pragma unroll
  for (int fm = 0; fm < 2; ++fm) {
    int p = wm * 32 + fm * 16 + l15;
    arow[fm] = p / CX;
    acolb[fm] = p % CX;
  }

  auto bload = [&](int hl, int fn, int kcc, int tap) -> short8 {
    int cof = cog * 4 + wn * 2 + fn;
    return Wr[((((size_t)hl * ncof + cof) * nkc + kcc) * 9 + tap) * 64 + lane];
  };
  auto gload = [&](int kcc, int idx) -> short8 {
    int g = idx & 3, cix = idx >> 2;
    int col = cix % COLS, row = cix / COLS;
    int sy = y0 + row - 1;
    int sx = x0 + col - 1;
    short8 v = {};
    if (sy >= 0 && sy < Hout && sx >= 0 && sx < Wout) {
      int ry = S ? 2 * sy : sy, rx = S ? 2 * sx : sx;
      v = *reinterpret_cast<const short8*>(
          reinterpret_cast<const short*>(src) +
          (((size_t)b * (S ? 2 * Hout : Hout) + ry) * Win + rx) * Cin +
          kcc * 32 + g * 8);
      if (stats) {
        const float2* st = stats + (size_t)b * Cin + kcc * 32 + g * 8;
#pragma unroll
        for (int j = 0; j < 8; ++j)
          v[j] = fbits((sb2f(v[j]) - st[j].x) * st[j].y);
      }
    }
    return v;
  };
  auto slot_of = [&](int idx) -> int {
    int g = idx & 3, cix = idx >> 2;
    int col = cix % COLS, row = cix / COLS;
    return (row * 4 + g) * COLS + col;
  };

  short8 bc00 = bload(0, 0, 0, 0), bc01 = bload(0, 1, 0, 0);
  short8 bc10 = bload(1, 0, 0, 0), bc11 = bload(1, 1, 0, 0);

  {
    short8 s0 = {}, s1 = {};
    if (tid < NGR) s0 = gload(0, tid);
    if (tid + 256 < NGR) s1 = gload(0, tid + 256);
    if (tid < NGR) a_s[slot_of(tid)] = s0;
    if (tid + 256 < NGR) a_s[slot_of(tid + 256)] = s1;
  }
  __syncthreads();

  for (int kc = 0; kc < nkc; ++kc) {
    short8 s0 = {}, s1 = {};
    const bool more = (kc + 1 < nkc);
    if (more) {
      if (tid < NGR) s0 = gload(kc + 1, tid);
      if (tid + 256 < NGR) s1 = gload(kc + 1, tid + 256);
    }

#pragma unroll
    for (int tap = 0; tap < 9; ++tap) {
      const int dy = tap / 3, dx = tap % 3;
      int nt = tap + 1, nk = kc;
      if (nt == 9) { nt = 0; nk = (kc + 1 < nkc) ? kc + 1 : 0; }
      short8 bn00 = bload(0, 0, nk, nt), bn01 = bload(0, 1, nk, nt);
      short8 bn10 = bload(1, 0, nk, nt), bn11 = bload(1, 1, nk, nt);
      short8 a0 = a_s[((arow[0] + dy) * 4 + lg) * COLS + acolb[0] + dx];
      short8 a1 = a_s[((arow[1] + dy) * 4 + lg) * COLS + acolb[1] + dx];
      acc[0][0] = __builtin_amdgcn_mfma_f32_16x16x32_bf16(a0, bc00, acc[0][0], 0, 0, 0);
      acc[0][0] = __builtin_amdgcn_mfma_f32_16x16x32_bf16(a0, bc10, acc[0][0], 0, 0, 0);
      acc[0][1] = __builtin_amdgcn_mfma_f32_16x16x32_bf16(a0, bc01, acc[0][1], 0, 0, 0);
      acc[0][1] = __builtin_amdgcn_mfma_f32_16x16x32_bf16(a0, bc11, acc[0][1], 0, 0, 0);
      acc[1][0] = __builtin_amdgcn_mfma_f32_16x16x32_bf16(a1, bc00, acc[1][0], 0, 0, 0);
      acc[1][0] = __builtin_amdgcn_mfma_f32_16x16x32_bf16(a1, bc10, acc[1][0], 0, 0, 0);
      acc[1][1] = __builtin_amdgcn_mfma_f32_16x16x32_bf16(a1, bc01, acc[1][1], 0, 0, 0);
      acc[1][1] = __builtin_amdgcn_mfma_f32_16x16x32_bf16(a1, bc11, acc[1][1], 0, 0, 0);
      bc00 = bn00; bc01 = bn01; bc10 = bn10; bc11 = bn11;
    }

    if (more) {
      __syncthreads();
      if (tid < NGR) a_s[slot_of(tid)] = s0;
      if (tid + 256 < NGR) a_s[slot_of(tid + 256)] = s1;
      __syncthreads();
    }
  }

#pragma unroll
  for (int fn = 0; fn < 2; ++fn) {
    int co = cog * 64 + wn * 32 + fn * 16 + l15;
    float bs = bias[co];
#pragma unroll
    for (int fm = 0; fm < 2; ++fm) {
#pragma unroll
      for (int j = 0; j < 4; ++j) {
        int p = wm * 32 + fm * 16 + lg * 4 + j;
        int r = p / CX, x = p % CX;
        float v = fmaxf(acc[fm][fn][j] + bs, 0.f);
        dst[((size_t)(b * Hout + y0 + r) * Wout + x0 + x) * Cout + co] = f2b(v);
      }
    }
  }
}

// ---------------------------------------------------------------------------
// conv1a: Cin=2 VALU direct conv. NCHW f32 color (subsample-then-conv),
// NHWC bf16 out, bias+ReLU.
// ---------------------------------------------------------------------------
__global__ __launch_bounds__(256) void conv1a_k(
    const float* __restrict__ src, bf16* __restrict__ dst,
    const float* __restrict__ w, const float* __restrict__ bias)
{
  const int b = blockIdx.z, cog = blockIdx.y;
  const int ty0 = (blockIdx.x / 16) * 16, tx0 = (blockIdx.x % 16) * 16;
  const int tid = threadIdx.x, tx = tid & 15, ty = tid >> 4;

  __shared__ float in_s[2][18][18];
  __shared__ __align__(16) float w_s[2][3][3][16];

  for (int idx = tid; idx < 2 * 324; idx += 256) {
    int ci = idx / 324, r = idx - ci * 324;
    int iy = r / 18, ix = r - iy * 18;
    int gy = ty0 + iy - 1, gx = tx0 + ix - 1;
    float v = 0.f;
    if (gy >= 0 && gy < 256 && gx >= 0 && gx < 256)
      v = src[((size_t)(b * 2 + ci) * 512 + 2 * gy) * 512 + 2 * gx];
    in_s[ci][iy][ix] = v;
  }
  for (int idx = tid; idx < 2 * 144; idx += 256) {
    int co = idx & 15, r = idx >> 4;
    int ci = r / 9, k = r - ci * 9;
    w_s[ci][k / 3][k % 3][co] = w[(size_t)((cog * 16 + co) * 2 + ci) * 9 + k];
  }
  __syncthreads();

  float acc[16];
#pragma unroll
  for (int i = 0; i < 16; ++i) acc[i] = 0.f;
  for (int ci = 0; ci < 2; ++ci)
#pragma unroll
    for (int dy = 0; dy < 3; ++dy)
#pragma unroll
      for (int dx = 0; dx < 3; ++dx) {
        float v = in_s[ci][ty + dy][tx + dx];
        const float4* wv = (const float4*)(&w_s[ci][dy][dx][0]);
        float4 w0 = wv[0], w1 = wv[1], w2 = wv[2], w3 = wv[3];
        acc[0] = fmaf(v, w0.x, acc[0]);   acc[1] = fmaf(v, w0.y, acc[1]);
        acc[2] = fmaf(v, w0.z, acc[2]);   acc[3] = fmaf(v, w0.w, acc[3]);
        acc[4] = fmaf(v, w1.x, acc[4]);   acc[5] = fmaf(v, w1.y, acc[5]);
        acc[6] = fmaf(v, w1.z, acc[6]);   acc[7] = fmaf(v, w1.w, acc[7]);
        acc[8] = fmaf(v, w2.x, acc[8]);   acc[9] = fmaf(v, w2.y, acc[9]);
        acc[10] = fmaf(v, w2.z, acc[10]); acc[11] = fmaf(v, w2.w, acc[11]);
        acc[12] = fmaf(v, w3.x, acc[12]); acc[13] = fmaf(v, w3.y, acc[13]);
        acc[14] = fmaf(v, w3.z, acc[14]); acc[15] = fmaf(v, w3.w, acc[15]);
      }

  const int gy = ty0 + ty, gx = tx0 + tx;
  short8 s0, s1;
#pragma unroll
  for (int j = 0; j < 8; ++j) {
    s0[j] = fbits(fmaxf(acc[j] + bias[cog * 16 + j], 0.f));
    s1[j] = fbits(fmaxf(acc[8 + j] + bias[cog * 16 + 8 + j], 0.f));
  }
  short8* dp = reinterpret_cast<short8*>(
      reinterpret_cast<short*>(dst) + (((size_t)(b * 256 + gy) * 256 + gx) * 64 + cog * 16));
  dp[0] = s0; dp[1] = s1;
}

// ---------------------------------------------------------------------------
// InstanceNorm stats, 2-level. stats1 REWRITTEN: vectorized short8 loads
// (8 channels/thread), thread = (c8-group, px-group), pgc = 256/(C/8)
// px-groups; LDS [2][2048] reduce. Grid (PC, nb); partial layout unchanged.
// ---------------------------------------------------------------------------
__global__ __launch_bounds__(256) void inorm_stats1_k(
    const bf16* __restrict__ x, float2* __restrict__ part,
    int HW, int C, int nb, int PC)
{
  const int b = blockIdx.y, pc = blockIdx.x;
  const int NC8 = C >> 3;
  const int pgc = 256 / NC8;                 // 32,16,8,4
  const int c8 = (threadIdx.x % NC8) * 8;
  const int pg = threadIdx.x / NC8;
  const int chunk = HW / PC;
  const int p0 = pc * chunk;

  float s[8] = {}, ss[8] = {};
  for (int p = p0 + pg; p < p0 + chunk; p += pgc) {
    short8 v = *reinterpret_cast<const short8*>(
        reinterpret_cast<const short*>(x) + ((size_t)b * HW + p) * C + c8);
#pragma unroll
    for (int j = 0; j < 8; ++j) {
      float f = sb2f(v[j]);
      s[j] += f; ss[j] += f * f;
    }
  }
  __shared__ float sh[2][2048];              // pgc*C == 2048 always
#pragma unroll
  for (int j = 0; j < 8; ++j) {
    sh[0][pg * C + c8 + j] = s[j];
    sh[1][pg * C + c8 + j] = ss[j];
  }
  __syncthreads();
  for (int c = threadIdx.x; c < C; c += 256) {
    float as = 0.f, aq = 0.f;
    for (int g = 0; g < pgc; ++g) { as += sh[0][g * C + c]; aq += sh[1][g * C + c]; }
    part[((size_t)pc * nb + b) * C + c] = make_float2(as, aq);
  }
}

__global__ __launch_bounds__(256) void inorm_stats2_k(
    const float2* __restrict__ part, float2* __restrict__ stats,
    int HW, int C, int PC, int nb)
{
  const int b = blockIdx.y, cg = blockIdx.x;
  const int c = threadIdx.x & 63, i = threadIdx.x >> 6;
  float s = 0.f, ss = 0.f;
  for (int pc = i; pc < PC; pc += 4) {
    float2 v = part[((size_t)pc * nb + b) * C + cg * 64 + c];
    s += v.x; ss += v.y;
  }
  __shared__ float sh[2][4][64];
  sh[0][i][c] = s; sh[1][i][c] = ss;
  __syncthreads();
  if (threadIdx.x < 64) {
    int cc = threadIdx.x;
    float s4 = sh[0][0][cc] + sh[0][1][cc] + sh[0][2][cc] + sh[0][3][cc];
    float q4 = sh[1][0][cc] + sh[1][1][cc] + sh[1][2][cc] + sh[1][3][cc];
    float m = s4 / (float)HW;
    float var = q4 / (float)HW - m * m;
    stats[(size_t)b * C + cg * 64 + cc] = make_float2(m, rsqrtf(var + 1e-5f));
  }
}

// generic apply: NHWC bf16 -> {NHWC bf16, NCHW f32} dests
__global__ __launch_bounds__(256) void inorm_apply_k(
    const bf16* __restrict__ x, const float2* __restrict__ stats, int HW, int C,
    bf16* __restrict__ dnhwc, float* __restrict__ fnchw)
{
  const int b = blockIdx.z, cg = blockIdx.y;
  const int c = cg * 64 + (threadIdx.x & 63);
  const int p = blockIdx.x * 4 + (threadIdx.x >> 6);
  const float2 st = stats[(size_t)b * C + c];
  const size_t ia = ((size_t)b * HW + p) * C + c;
  const float v = (b2f(x[ia]) - st.x) * st.y;
  if (dnhwc) dnhwc[ia] = f2b(v);
  if (fnchw) fnchw[((size_t)(b * C + c)) * HW + p] = v;
}

// ---------------------------------------------------------------------------
// Stage-2 apply: NHWC bf16 -> x-padded NCHW bf16 [b][c][128][144]
// ---------------------------------------------------------------------------
__global__ __launch_bounds__(256) void inorm_apply_pad_k(
    const bf16* __restrict__ x, const float2* __restrict__ stats,
    bf16* __restrict__ pad)
{
  const int b = blockIdx.z, cg = blockIdx.y, yy = blockIdx.x;
  const int tid = threadIdx.x;
  __shared__ bf16 t_s[64][130];
  __shared__ float2 st_s[64];
  if (tid < 64) st_s[tid] = stats[(size_t)b * 128 + cg * 64 + tid];
  __syncthreads();

  const int c8 = (tid & 7) * 8, px0 = tid >> 3;
#pragma unroll
  for (int pass = 0; pass < 4; ++pass) {
    int px = pass * 32 + px0;
    short8 v = *reinterpret_cast<const short8*>(
        reinterpret_cast<const short*>(x) +
        ((size_t)(b * 16384 + yy * 128 + px) * 128 + cg * 64 + c8));
#pragma unroll
    for (int j = 0; j < 8; ++j) {
      float2 st = st_s[c8 + j];
      t_s[c8 + j][px] = f2b((sb2f(v[j]) - st.x) * st.y);
    }
  }
  __syncthreads();

  for (int idx = tid; idx < 64 * 18; idx += 256) {
    int c = idx / 18, g = idx - (idx / 18) * 18;
    short8 v;
#pragma unroll
    for (int j = 0; j < 8; ++j) {
      int xx = g * 8 + j - 6;
      xx = xx < 0 ? 0 : (xx > 127 ? 127 : xx);
      v[j] = *reinterpret_cast<short*>(&t_s[c][xx]);
    }
    *reinterpret_cast<short8*>(
        reinterpret_cast<short*>(pad) +
        ((size_t)(b * 128 + cg * 64 + c) * 128 + yy) * 144 + g * 8) = v;
  }
}

// ---------------------------------------------------------------------------
// Correlation via MFMA banded GEMM (r11 structure, b0 batch-split).
// ---------------------------------------------------------------------------
__global__ __launch_bounds__(256) void corr_mfma_k(
    const float* __restrict__ corr, const bf16* __restrict__ pad,
    float* __restrict__ outc, bf16* __restrict__ outn, int b0)
{
  __shared__ __align__(16) char smem[26 * 64 * 16];
  short8* a_lds = reinterpret_cast<short8*>(smem);
  float* out_s = reinterpret_cast<float*>(smem);

  const int b = b0 + blockIdx.z;
  const int wg = xcd_swz(blockIdx.x, gridDim.x);
  const int y = wg >> 3, xt = wg & 7;
  const int x0 = xt * 16;
  const int tid = threadIdx.x, lane = tid & 63, wid = tid >> 6;
  const int l15 = lane & 15, lg = lane >> 4;

  for (int idx = tid; idx < 26 * 64; idx += 256) {
    short8 z = {};
    a_lds[idx] = z;
  }
  __syncthreads();

  unsigned short* ah = reinterpret_cast<unsigned short*>(a_lds);
  for (int idx = tid; idx < 169 * 16; idx += 256) {
    int t = idx >> 4, m = idx & 15;
    int dy = t / 13, dx = t - dy * 13;
    float f = corr[((size_t)b * 169 + t) * 16384 + y * 128 + x0 + m];
    bf16 hi = f2b(f);
    unsigned short hb = *reinterpret_cast<unsigned short*>(&hi);
    unsigned short lb = (unsigned short)fbits(f - b2f(hi));
    int k = m + dx;
    int ent = dy * 64 + (k >> 3) * 16 + m;
    ah[ent * 8 + (k & 7)] = hb;
    ah[(13 * 64 + ent) * 8 + (k & 7)] = lb;
  }
  __syncthreads();

  const int cg0 = wid * 2;
  f32x4 acc0 = {}, acc1 = {};
  const short* pb = reinterpret_cast<const short*>(pad);

  for (int dy = 0; dy < 13; ++dy) {
    int rowc = y + dy - 6; rowc = rowc < 0 ? 0 : (rowc > 127 ? 127 : rowc);
    short8 bhi = a_lds[dy * 64 + lane];
    short8 blo = a_lds[(13 + dy) * 64 + lane];
    size_t base0 = ((size_t)(b * 128 + cg0 * 16 + l15) * 128 + rowc) * 144
                   + x0 + lg * 8;
    short8 a0 = *reinterpret_cast<const short8*>(pb + base0);
    short8 a1 = *reinterpret_cast<const short8*>(pb + base0 + (size_t)16 * 128 * 144);
    acc0 = __builtin_amdgcn_mfma_f32_16x16x32_bf16(a0, bhi, acc0, 0, 0, 0);
    acc1 = __builtin_amdgcn_mfma_f32_16x16x32_bf16(a1, bhi, acc1, 0, 0, 0);
    acc0 = __builtin_amdgcn_mfma_f32_16x16x32_bf16(a0, blo, acc0, 0, 0, 0);
    acc1 = __builtin_amdgcn_mfma_f32_16x16x32_bf16(a1, blo, acc1, 0, 0, 0);
  }
  __syncthreads();

#pragma unroll
  for (int cgi = 0; cgi < 2; ++cgi) {
    f32x4 a = cgi ? acc1 : acc0;
    float* dst4 = out_s + l15 * 132 + (cg0 + cgi) * 16 + lg * 4;
    *reinterpret_cast<f32x4*>(dst4) = a;
  }
  __syncthreads();

  {
    int px_ = tid >> 4, c8 = (tid & 15) * 8;
    const float* row = out_s + px_ * 132 + c8;
    short8 v;
#pragma unroll
    for (int j = 0; j < 8; ++j) v[j] = fbits(row[j]);
    *reinterpret_cast<short8*>(
        reinterpret_cast<short*>(outn) +
        ((size_t)(b * 16384 + y * 128 + x0 + px_)) * 128 + c8) = v;
  }
  {
    int ch = tid >> 1, pg = tid & 1;
    float v0[4], v1[4];
#pragma unroll
    for (int i = 0; i < 4; ++i) v0[i] = out_s[(pg * 8 + i) * 132 + ch];
#pragma unroll
    for (int i = 0; i < 4; ++i) v1[i] = out_s[(pg * 8 + 4 + i) * 132 + ch];
    float* dst = outc + ((size_t)(b * 128 + ch)) * 16384 + y * 128 + x0 + pg * 8;
    *reinterpret_cast<float4*>(dst) = make_float4(v0[0], v0[1], v0[2], v0[3]);
    *reinterpret_cast<float4*>(dst + 4) = make_float4(v1[0], v1[1], v1[2], v1[3]);
  }
}

// ---------------------------------------------------------------------------
// Workspace plan — BYTES, liveness-proven (round-5/6 table). Peak 62.9 MB.
// ---------------------------------------------------------------------------
extern "C" void kernel_launch(void* const* d_in, const int* in_sizes, int n_in,
                              void* d_out, int out_size, void* d_ws, size_t ws_size,
                              hipStream_t stream) {
  const float* color = (const float*)d_in[0];
  const float* corr  = (const float*)d_in[1];
  const float* w1a = (const float*)d_in[2];  const float* b1a = (const float*)d_in[3];
  const float* w1b = (const float*)d_in[4];  const float* b1b = (const float*)d_in[5];
  const float* w2a = (const float*)d_in[6];  const float* b2a = (const float*)d_in[7];
  const float* w2b = (const float*)d_in[8];  const float* b2b = (const float*)d_in[9];
  const float* w3a = (const float*)d_in[10]; const float* b3a = (const float*)d_in[11];
  const float* w3b = (const float*)d_in[12]; const float* b3b = (const float*)d_in[13];
  const float* w4a = (const float*)d_in[14]; const float* b4a = (const float*)d_in[15];
  const float* w4b = (const float*)d_in[16]; const float* b4b = (const float*)d_in[17];

  float* out = (float*)d_out;
  char* ws = (char*)d_ws;
  const size_t MB = 1048576;
  float2* stats = (float2*)ws;
  float2* part  = (float2*)(ws + (64 << 10));
  short*  WrS   = (short*)(ws + (256 << 10));
  const short8* Wr = (const short8*)WrS;
  bf16* P0 = (bf16*)(ws + 10 * MB);
  bf16* P1 = (bf16*)(ws + 27 * MB);
  bf16* P2 = (bf16*)(ws + 44 * MB);
  bf16* X1 = P0;
  bf16* X2 = (bf16*)d_out;
  const float2* nost = (const float2*)nullptr;

  // ---- stage 1: conv1a -> conv1b -> stats (apply fused into conv2a) ----
  conv1a_k<<<dim3(256, 4, 4), 256, 0, stream>>>(color, X1, w1a, b1a);
  repack_k<<<36, 256, 0, stream>>>(w1b, WrS, 64, 64);
  conv_mfma_k<4, 16, 0><<<dim3(64 * 16, 1, 4), 256, 0, stream>>>(
      X1, X2, Wr, b1b, nost, 256, 256, 256, 64, 64, 16);
  inorm_stats1_k<<<dim3(64, 4), 256, 0, stream>>>(X2, part, 65536, 64, 4, 64);
  inorm_stats2_k<<<dim3(1, 4), 256, 0, stream>>>(part, stats, 65536, 64, 64, 4);

  // ---- stage 2: conv2a (raw X2 + stats) -> conv2b -> pad apply ----
  repack_k<<<72, 256, 0, stream>>>(w2a, WrS, 64, 128);
  conv_mfma_k<4, 16, 1><<<dim3(32 * 8, 2, 4), 256, 0, stream>>>(
      X2, P0, Wr, b2a, stats, 256, 128, 128, 64, 128, 8);
  repack_k<<<144, 256, 0, stream>>>(w2b, WrS, 128, 128);
  conv_mfma_k<4, 16, 0><<<dim3(32 * 8, 2, 4), 256, 0, stream>>>(
      P0, P1, Wr, b2b, nost, 128, 128, 128, 128, 128, 8);
  inorm_stats1_k<<<dim3(64, 4), 256, 0, stream>>>(P1, part, 16384, 128, 4, 64);
  inorm_stats2_k<<<dim3(2, 4), 256, 0, stream>>>(part, stats, 16384, 128, 64, 4);
  inorm_apply_pad_k<<<dim3(128, 2, 4), 256, 0, stream>>>(P1, stats, P2);

  // ---- correlation (MFMA), split into 2 half-batch dispatches ----
  corr_mfma_k<<<dim3(128 * 8, 1, 2), 256, 0, stream>>>(corr, P2, out, P0, 0);
  corr_mfma_k<<<dim3(128 * 8, 1, 2), 256, 0, stream>>>(corr, P2, out, P0, 2);

  // ---- stage 3: conv3a -> conv3b -> stats; apply writes f32 only ----
  repack_k<<<288, 256, 0, stream>>>(w3a, WrS, 128, 256);
  conv_mfma_k<4, 16, 1><<<dim3(16 * 4, 4, 4), 256, 0, stream>>>(
      P0, P1, Wr, b3a, nost, 128, 64, 64, 128, 256, 4);
  repack_k<<<576, 256, 0, stream>>>(w3b, WrS, 256, 256);
  conv_mfma_k<4, 16, 0><<<dim3(16 * 4, 4, 4), 256, 0, stream>>>(
      P1, P2, Wr, b3b, nost, 64, 64, 64, 256, 256, 4);
  inorm_stats1_k<<<dim3(32, 4), 256, 0, stream>>>(P2, part, 4096, 256, 4, 32);
  inorm_stats2_k<<<dim3(4, 4), 256, 0, stream>>>(part, stats, 4096, 256, 32, 4);
  inorm_apply_k<<<dim3(1024, 4, 4), 256, 0, stream>>>(
      P2, stats, 4096, 256, (bf16*)nullptr, out + 8388608);

  // ---- stage 4: conv4a (raw P2 + stats) -> conv4b -> inorm ----
  repack_k<<<1152, 256, 0, stream>>>(w4a, WrS, 256, 512);
  conv_mfma_k<4, 16, 1><<<dim3(8 * 2, 8, 4), 256, 0, stream>>>(
      P2, P1, Wr, b4a, stats, 64, 32, 32, 256, 512, 2);
  repack_k<<<2304, 256, 0, stream>>>(w4b, WrS, 512, 512);
  conv_mfma_k<4, 16, 0><<<dim3(8 * 2, 8, 4), 256, 0, stream>>>(
      P1, P2, Wr, b4b, nost, 32, 32, 32, 512, 512, 2);
  inorm_stats1_k<<<dim3(32, 4), 256, 0, stream>>>(P2, part, 1024, 512, 4, 32);
  inorm_stats2_k<<<dim3(8, 4), 256, 0, stream>>>(part, stats, 1024, 512, 32, 4);
  inorm_apply_k<<<dim3(256, 8, 4), 256, 0, stream>>>(
      P2, stats, 1024, 512, (bf16*)nullptr, out + 12582912);
}

// Round 18
// 496.539 us; speedup vs baseline: 1.5134x; 1.0032x over previous
//
#include <hip/hip_runtime.h>
#include <hip/hip_bf16.h>

typedef __hip_bfloat16 bf16;
typedef __attribute__((ext_vector_type(8))) short short8;
typedef __attribute__((ext_vector_type(4))) float f32x4;

__device__ __forceinline__ float b2f(bf16 v) { return __bfloat162float(v); }
__device__ __forceinline__ bf16 f2b(float v) { return __float2bfloat16(v); }
__device__ __forceinline__ short fbits(float v) {
  bf16 h = f2b(v); return *reinterpret_cast<short*>(&h);
}
__device__ __forceinline__ float sb2f(short s) {
  return b2f(*reinterpret_cast<bf16*>(&s));
}
// bijective XCD swizzle (m204): contiguous grid chunk per XCD
__device__ __forceinline__ int xcd_swz(int bid, int nwg) {
  int q = nwg >> 3, r = nwg & 7;
  int xcd = bid & 7, idx = bid >> 3;
  return (xcd < r ? xcd * (q + 1) : r * (q + 1) + (xcd - r) * q) + idx;
}

// ---------------------------------------------------------------------------
// Weight repack: w[co][ci][ky][kx] f32  ->  B-fragment order, hi/lo bf16 split.
// ---------------------------------------------------------------------------
__global__ __launch_bounds__(256) void repack_k(
    const float* __restrict__ w, short* __restrict__ Wr, int Cin, int Cout)
{
  const int nkc = Cin >> 5, ncof = Cout >> 4;
  const size_t gid = (size_t)blockIdx.x * 256 + threadIdx.x;
  const int lane = gid & 63;
  size_t r = gid >> 6;
  const int tap = r % 9; r /= 9;
  const int kcc = r % nkc; r /= nkc;
  const int cof = r % ncof;
  const int hl = r / ncof;
  const int co = cof * 16 + (lane & 15);
  short8 v;
#pragma unroll
  for (int j = 0; j < 8; ++j) {
    int ci = kcc * 32 + ((lane >> 4) * 8 + j);
    float wv = w[((size_t)co * Cin + ci) * 9 + tap];
    bf16 hi = f2b(wv);
    v[j] = hl ? fbits(wv - b2f(hi)) : *reinterpret_cast<short*>(&hi);
  }
  *reinterpret_cast<short8*>(Wr + gid * 8) = v;
}

// ---------------------------------------------------------------------------
// MFMA implicit-GEMM 3x3 conv, BIG-TILE: block = R*CX px x 64 cout;
// wave = FM = R*CX/32 px-fragments x 32 co. 4x bigger tile => 4x less
// weight L2 traffic per FLOP (the r17-counter-diagnosed limiter).
// Optional `stats` fused during staging (bit-exact inorm apply).
// Per-acc hi->lo order per tap preserved -> bit-exact vs r17.
// S=1: conv on the SUBSAMPLED image (subsample-then-pad-conv).
// ---------------------------------------------------------------------------
template<int R, int CX, int S>
__global__ __launch_bounds__(256) void conv_mfma_k(
    const bf16* __restrict__ src, bf16* __restrict__ dst,
    const short8* __restrict__ Wr, const float* __restrict__ bias,
    const float2* __restrict__ stats,
    int Win, int Hout, int Wout, int Cin, int Cout, int XT)
{
  constexpr int ROWS = R + 2;
  constexpr int COLS = CX + 2;
  constexpr int NGR = ROWS * 4 * COLS;
  constexpr int FM = (R * CX) / 32;
  __shared__ short8 a_s[NGR];

  const int b = blockIdx.z, cog = blockIdx.y;
  const int xt = blockIdx.x % XT, yt = blockIdx.x / XT;
  const int x0 = xt * CX, y0 = yt * R;
  const int tid = threadIdx.x, lane = tid & 63, wid = tid >> 6;
  const int wm = wid & 1, wn = wid >> 1;
  const int nkc = Cin >> 5;
  const int ncof = Cout >> 4;
  const int l15 = lane & 15, lg = lane >> 4;

  f32x4 acc[FM][2] = {};

  int arow[FM], acolb[FM];
#pragma unroll
  for (int fm = 0; fm < FM; ++fm) {
    int p = wm * (R * CX / 2) + fm * 16 + l15;
    arow[fm] = p / CX;
    acolb[fm] = p % CX;
  }

  auto bload = [&](int hl, int fn, int kcc, int tap) -> short8 {
    int cof = cog * 4 + wn * 2 + fn;
    return Wr[((((size_t)hl * ncof + cof) * nkc + kcc) * 9 + tap) * 64 + lane];
  };

  short8 bc[2][2], bn_[2][2];
  bc[0][0] = bload(0, 0, 0, 0); bc[0][1] = bload(0, 1, 0, 0);
  bc[1][0] = bload(1, 0, 0, 0); bc[1][1] = bload(1, 1, 0, 0);

  for (int kc = 0; kc < nkc; ++kc) {
    __syncthreads();
    for (int idx = tid; idx < NGR; idx += 256) {
      int g = idx & 3, cix = idx >> 2;
      int col = cix % COLS, row = cix / COLS;
      int sy = y0 + row - 1;
      int sx = x0 + col - 1;
      short8 v = {};
      if (sy >= 0 && sy < Hout && sx >= 0 && sx < Wout) {
        int ry = S ? 2 * sy : sy, rx = S ? 2 * sx : sx;
        v = *reinterpret_cast<const short8*>(
            reinterpret_cast<const short*>(src) +
            (((size_t)b * (S ? 2 * Hout : Hout) + ry) * Win + rx) * Cin +
            kc * 32 + g * 8);
        if (stats) {                     // fused inorm apply (bit-exact)
          const float2* st = stats + (size_t)b * Cin + kc * 32 + g * 8;
#pragma unroll
          for (int j = 0; j < 8; ++j)
            v[j] = fbits((sb2f(v[j]) - st[j].x) * st[j].y);
        }
      }
      a_s[(row * 4 + g) * COLS + col] = v;
    }
    __syncthreads();

#pragma unroll
    for (int tap = 0; tap < 9; ++tap) {
      const int dy = tap / 3, dx = tap % 3;
      int nt = tap + 1, nk = kc;
      if (nt == 9) { nt = 0; nk = (kc + 1 < nkc) ? kc + 1 : 0; }
      bn_[0][0] = bload(0, 0, nk, nt); bn_[0][1] = bload(0, 1, nk, nt);
      bn_[1][0] = bload(1, 0, nk, nt); bn_[1][1] = bload(1, 1, nk, nt);
#pragma unroll
      for (int fm = 0; fm < FM; ++fm) {
        short8 a = a_s[((arow[fm] + dy) * 4 + lg) * COLS + acolb[fm] + dx];
        acc[fm][0] = __builtin_amdgcn_mfma_f32_16x16x32_bf16(a, bc[0][0], acc[fm][0], 0, 0, 0);
        acc[fm][0] = __builtin_amdgcn_mfma_f32_16x16x32_bf16(a, bc[1][0], acc[fm][0], 0, 0, 0);
        acc[fm][1] = __builtin_amdgcn_mfma_f32_16x16x32_bf16(a, bc[0][1], acc[fm][1], 0, 0, 0);
        acc[fm][1] = __builtin_amdgcn_mfma_f32_16x16x32_bf16(a, bc[1][1], acc[fm][1], 0, 0, 0);
      }
      bc[0][0] = bn_[0][0]; bc[0][1] = bn_[0][1];
      bc[1][0] = bn_[1][0]; bc[1][1] = bn_[1][1];
    }
  }

#pragma unroll
  for (int fn = 0; fn < 2; ++fn) {
    int co = cog * 64 + wn * 32 + fn * 16 + l15;
    float bs = bias[co];
#pragma unroll
    for (int fm = 0; fm < FM; ++fm) {
#pragma unroll
      for (int j = 0; j < 4; ++j) {
        int p = wm * (R * CX / 2) + fm * 16 + lg * 4 + j;
        int r = p / CX, x = p % CX;
        float v = fmaxf(acc[fm][fn][j] + bs, 0.f);
        dst[((size_t)(b * Hout + y0 + r) * Wout + x0 + x) * Cout + co] = f2b(v);
      }
    }
  }
}

// ---------------------------------------------------------------------------
// conv1a: Cin=2 VALU direct conv. NCHW f32 color (subsample-then-conv),
// NHWC bf16 out, bias+ReLU.
// ---------------------------------------------------------------------------
__global__ __launch_bounds__(256) void conv1a_k(
    const float* __restrict__ src, bf16* __restrict__ dst,
    const float* __restrict__ w, const float* __restrict__ bias)
{
  const int b = blockIdx.z, cog = blockIdx.y;
  const int ty0 = (blockIdx.x / 16) * 16, tx0 = (blockIdx.x % 16) * 16;
  const int tid = threadIdx.x, tx = tid & 15, ty = tid >> 4;

  __shared__ float in_s[2][18][18];
  __shared__ __align__(16) float w_s[2][3][3][16];

  for (int idx = tid; idx < 2 * 324; idx += 256) {
    int ci = idx / 324, r = idx - ci * 324;
    int iy = r / 18, ix = r - iy * 18;
    int gy = ty0 + iy - 1, gx = tx0 + ix - 1;
    float v = 0.f;
    if (gy >= 0 && gy < 256 && gx >= 0 && gx < 256)
      v = src[((size_t)(b * 2 + ci) * 512 + 2 * gy) * 512 + 2 * gx];
    in_s[ci][iy][ix] = v;
  }
  for (int idx = tid; idx < 2 * 144; idx += 256) {
    int co = idx & 15, r = idx >> 4;
    int ci = r / 9, k = r - ci * 9;
    w_s[ci][k / 3][k % 3][co] = w[(size_t)((cog * 16 + co) * 2 + ci) * 9 + k];
  }
  __syncthreads();

  float acc[16];
#pragma unroll
  for (int i = 0; i < 16; ++i) acc[i] = 0.f;
  for (int ci = 0; ci < 2; ++ci)
#pragma unroll
    for (int dy = 0; dy < 3; ++dy)
#pragma unroll
      for (int dx = 0; dx < 3; ++dx) {
        float v = in_s[ci][ty + dy][tx + dx];
        const float4* wv = (const float4*)(&w_s[ci][dy][dx][0]);
        float4 w0 = wv[0], w1 = wv[1], w2 = wv[2], w3 = wv[3];
        acc[0] = fmaf(v, w0.x, acc[0]);   acc[1] = fmaf(v, w0.y, acc[1]);
        acc[2] = fmaf(v, w0.z, acc[2]);   acc[3] = fmaf(v, w0.w, acc[3]);
        acc[4] = fmaf(v, w1.x, acc[4]);   acc[5] = fmaf(v, w1.y, acc[5]);
        acc[6] = fmaf(v, w1.z, acc[6]);   acc[7] = fmaf(v, w1.w, acc[7]);
        acc[8] = fmaf(v, w2.x, acc[8]);   acc[9] = fmaf(v, w2.y, acc[9]);
        acc[10] = fmaf(v, w2.z, acc[10]); acc[11] = fmaf(v, w2.w, acc[11]);
        acc[12] = fmaf(v, w3.x, acc[12]); acc[13] = fmaf(v, w3.y, acc[13]);
        acc[14] = fmaf(v, w3.z, acc[14]); acc[15] = fmaf(v, w3.w, acc[15]);
      }

  const int gy = ty0 + ty, gx = tx0 + tx;
  short8 s0, s1;
#pragma unroll
  for (int j = 0; j < 8; ++j) {
    s0[j] = fbits(fmaxf(acc[j] + bias[cog * 16 + j], 0.f));
    s1[j] = fbits(fmaxf(acc[8 + j] + bias[cog * 16 + 8 + j], 0.f));
  }
  short8* dp = reinterpret_cast<short8*>(
      reinterpret_cast<short*>(dst) + (((size_t)(b * 256 + gy) * 256 + gx) * 64 + cog * 16));
  dp[0] = s0; dp[1] = s1;
}

// ---------------------------------------------------------------------------
// InstanceNorm stats, 2-level (r17 vectorized stats1).
// ---------------------------------------------------------------------------
__global__ __launch_bounds__(256) void inorm_stats1_k(
    const bf16* __restrict__ x, float2* __restrict__ part,
    int HW, int C, int nb, int PC)
{
  const int b = blockIdx.y, pc = blockIdx.x;
  const int NC8 = C >> 3;
  const int pgc = 256 / NC8;
  const int c8 = (threadIdx.x % NC8) * 8;
  const int pg = threadIdx.x / NC8;
  const int chunk = HW / PC;
  const int p0 = pc * chunk;

  float s[8] = {}, ss[8] = {};
  for (int p = p0 + pg; p < p0 + chunk; p += pgc) {
    short8 v = *reinterpret_cast<const short8*>(
        reinterpret_cast<const short*>(x) + ((size_t)b * HW + p) * C + c8);
#pragma unroll
    for (int j = 0; j < 8; ++j) {
      float f = sb2f(v[j]);
      s[j] += f; ss[j] += f * f;
    }
  }
  __shared__ float sh[2][2048];
#pragma unroll
  for (int j = 0; j < 8; ++j) {
    sh[0][pg * C + c8 + j] = s[j];
    sh[1][pg * C + c8 + j] = ss[j];
  }
  __syncthreads();
  for (int c = threadIdx.x; c < C; c += 256) {
    float as = 0.f, aq = 0.f;
    for (int g = 0; g < pgc; ++g) { as += sh[0][g * C + c]; aq += sh[1][g * C + c]; }
    part[((size_t)pc * nb + b) * C + c] = make_float2(as, aq);
  }
}

__global__ __launch_bounds__(256) void inorm_stats2_k(
    const float2* __restrict__ part, float2* __restrict__ stats,
    int HW, int C, int PC, int nb)
{
  const int b = blockIdx.y, cg = blockIdx.x;
  const int c = threadIdx.x & 63, i = threadIdx.x >> 6;
  float s = 0.f, ss = 0.f;
  for (int pc = i; pc < PC; pc += 4) {
    float2 v = part[((size_t)pc * nb + b) * C + cg * 64 + c];
    s += v.x; ss += v.y;
  }
  __shared__ float sh[2][4][64];
  sh[0][i][c] = s; sh[1][i][c] = ss;
  __syncthreads();
  if (threadIdx.x < 64) {
    int cc = threadIdx.x;
    float s4 = sh[0][0][cc] + sh[0][1][cc] + sh[0][2][cc] + sh[0][3][cc];
    float q4 = sh[1][0][cc] + sh[1][1][cc] + sh[1][2][cc] + sh[1][3][cc];
    float m = s4 / (float)HW;
    float var = q4 / (float)HW - m * m;
    stats[(size_t)b * C + cg * 64 + cc] = make_float2(m, rsqrtf(var + 1e-5f));
  }
}

// generic apply: NHWC bf16 -> {NHWC bf16, NCHW f32} dests
__global__ __launch_bounds__(256) void inorm_apply_k(
    const bf16* __restrict__ x, const float2* __restrict__ stats, int HW, int C,
    bf16* __restrict__ dnhwc, float* __restrict__ fnchw)
{
  const int b = blockIdx.z, cg = blockIdx.y;
  const int c = cg * 64 + (threadIdx.x & 63);
  const int p = blockIdx.x * 4 + (threadIdx.x >> 6);
  const float2 st = stats[(size_t)b * C + c];
  const size_t ia = ((size_t)b * HW + p) * C + c;
  const float v = (b2f(x[ia]) - st.x) * st.y;
  if (dnhwc) dnhwc[ia] = f2b(v);
  if (fnchw) fnchw[((size_t)(b * C + c)) * HW + p] = v;
}

// ---------------------------------------------------------------------------
// Stage-2 apply: NHWC bf16 -> x-padded NCHW bf16 [b][c][128][144]
// ---------------------------------------------------------------------------
__global__ __launch_bounds__(256) void inorm_apply_pad_k(
    const bf16* __restrict__ x, const float2* __restrict__ stats,
    bf16* __restrict__ pad)
{
  const int b = blockIdx.z, cg = blockIdx.y, yy = blockIdx.x;
  const int tid = threadIdx.x;
  __shared__ bf16 t_s[64][130];
  __shared__ float2 st_s[64];
  if (tid < 64) st_s[tid] = stats[(size_t)b * 128 + cg * 64 + tid];
  __syncthreads();

  const int c8 = (tid & 7) * 8, px0 = tid >> 3;
#pragma unroll
  for (int pass = 0; pass < 4; ++pass) {
    int px = pass * 32 + px0;
    short8 v = *reinterpret_cast<const short8*>(
        reinterpret_cast<const short*>(x) +
        ((size_t)(b * 16384 + yy * 128 + px) * 128 + cg * 64 + c8));
#pragma unroll
    for (int j = 0; j < 8; ++j) {
      float2 st = st_s[c8 + j];
      t_s[c8 + j][px] = f2b((sb2f(v[j]) - st.x) * st.y);
    }
  }
  __syncthreads();

  for (int idx = tid; idx < 64 * 18; idx += 256) {
    int c = idx / 18, g = idx - (idx / 18) * 18;
    short8 v;
#pragma unroll
    for (int j = 0; j < 8; ++j) {
      int xx = g * 8 + j - 6;
      xx = xx < 0 ? 0 : (xx > 127 ? 127 : xx);
      v[j] = *reinterpret_cast<short*>(&t_s[c][xx]);
    }
    *reinterpret_cast<short8*>(
        reinterpret_cast<short*>(pad) +
        ((size_t)(b * 128 + cg * 64 + c) * 128 + yy) * 144 + g * 8) = v;
  }
}

// ---------------------------------------------------------------------------
// Correlation via MFMA banded GEMM (r11 structure, b0 batch-split).
// ---------------------------------------------------------------------------
__global__ __launch_bounds__(256) void corr_mfma_k(
    const float* __restrict__ corr, const bf16* __restrict__ pad,
    float* __restrict__ outc, bf16* __restrict__ outn, int b0)
{
  __shared__ __align__(16) char smem[26 * 64 * 16];
  short8* a_lds = reinterpret_cast<short8*>(smem);
  float* out_s = reinterpret_cast<float*>(smem);

  const int b = b0 + blockIdx.z;
  const int wg = xcd_swz(blockIdx.x, gridDim.x);
  const int y = wg >> 3, xt = wg & 7;
  const int x0 = xt * 16;
  const int tid = threadIdx.x, lane = tid & 63, wid = tid >> 6;
  const int l15 = lane & 15, lg = lane >> 4;

  for (int idx = tid; idx < 26 * 64; idx += 256) {
    short8 z = {};
    a_lds[idx] = z;
  }
  __syncthreads();

  unsigned short* ah = reinterpret_cast<unsigned short*>(a_lds);
  for (int idx = tid; idx < 169 * 16; idx += 256) {
    int t = idx >> 4, m = idx & 15;
    int dy = t / 13, dx = t - dy * 13;
    float f = corr[((size_t)b * 169 + t) * 16384 + y * 128 + x0 + m];
    bf16 hi = f2b(f);
    unsigned short hb = *reinterpret_cast<unsigned short*>(&hi);
    unsigned short lb = (unsigned short)fbits(f - b2f(hi));
    int k = m + dx;
    int ent = dy * 64 + (k >> 3) * 16 + m;
    ah[ent * 8 + (k & 7)] = hb;
    ah[(13 * 64 + ent) * 8 + (k & 7)] = lb;
  }
  __syncthreads();

  const int cg0 = wid * 2;
  f32x4 acc0 = {}, acc1 = {};
  const short* pb = reinterpret_cast<const short*>(pad);

  for (int dy = 0; dy < 13; ++dy) {
    int rowc = y + dy - 6; rowc = rowc < 0 ? 0 : (rowc > 127 ? 127 : rowc);
    short8 bhi = a_lds[dy * 64 + lane];
    short8 blo = a_lds[(13 + dy) * 64 + lane];
    size_t base0 = ((size_t)(b * 128 + cg0 * 16 + l15) * 128 + rowc) * 144
                   + x0 + lg * 8;
    short8 a0 = *reinterpret_cast<const short8*>(pb + base0);
    short8 a1 = *reinterpret_cast<const short8*>(pb + base0 + (size_t)16 * 128 * 144);
    acc0 = __builtin_amdgcn_mfma_f32_16x16x32_bf16(a0, bhi, acc0, 0, 0, 0);
    acc1 = __builtin_amdgcn_mfma_f32_16x16x32_bf16(a1, bhi, acc1, 0, 0, 0);
    acc0 = __builtin_amdgcn_mfma_f32_16x16x32_bf16(a0, blo, acc0, 0, 0, 0);
    acc1 = __builtin_amdgcn_mfma_f32_16x16x32_bf16(a1, blo, acc1, 0, 0, 0);
  }
  __syncthreads();

#pragma unroll
  for (int cgi = 0; cgi < 2; ++cgi) {
    f32x4 a = cgi ? acc1 : acc0;
    float* dst4 = out_s + l15 * 132 + (cg0 + cgi) * 16 + lg * 4;
    *reinterpret_cast<f32x4*>(dst4) = a;
  }
  __syncthreads();

  {
    int px_ = tid >> 4, c8 = (tid & 15) * 8;
    const float* row = out_s + px_ * 132 + c8;
    short8 v;
#pragma unroll
    for (int j = 0; j < 8; ++j) v[j] = fbits(row[j]);
    *reinterpret_cast<short8*>(
        reinterpret_cast<short*>(outn) +
        ((size_t)(b * 16384 + y * 128 + x0 + px_)) * 128 + c8) = v;
  }
  {
    int ch = tid >> 1, pg = tid & 1;
    float v0[4], v1[4];
#pragma unroll
    for (int i = 0; i < 4; ++i) v0[i] = out_s[(pg * 8 + i) * 132 + ch];
#pragma unroll
    for (int i = 0; i < 4; ++i) v1[i] = out_s[(pg * 8 + 4 + i) * 132 + ch];
    float* dst = outc + ((size_t)(b * 128 + ch)) * 16384 + y * 128 + x0 + pg * 8;
    *reinterpret_cast<float4*>(dst) = make_float4(v0[0], v0[1], v0[2], v0[3]);
    *reinterpret_cast<float4*>(dst + 4) = make_float4(v1[0], v1[1], v1[2], v1[3]);
  }
}

// ---------------------------------------------------------------------------
// Workspace plan — BYTES, liveness-proven (round-5/6 table). Peak 62.9 MB.
// ---------------------------------------------------------------------------
extern "C" void kernel_launch(void* const* d_in, const int* in_sizes, int n_in,
                              void* d_out, int out_size, void* d_ws, size_t ws_size,
                              hipStream_t stream) {
  const float* color = (const float*)d_in[0];
  const float* corr  = (const float*)d_in[1];
  const float* w1a = (const float*)d_in[2];  const float* b1a = (const float*)d_in[3];
  const float* w1b = (const float*)d_in[4];  const float* b1b = (const float*)d_in[5];
  const float* w2a = (const float*)d_in[6];  const float* b2a = (const float*)d_in[7];
  const float* w2b = (const float*)d_in[8];  const float* b2b = (const float*)d_in[9];
  const float* w3a = (const float*)d_in[10]; const float* b3a = (const float*)d_in[11];
  const float* w3b = (const float*)d_in[12]; const float* b3b = (const float*)d_in[13];
  const float* w4a = (const float*)d_in[14]; const float* b4a = (const float*)d_in[15];
  const float* w4b = (const float*)d_in[16]; const float* b4b = (const float*)d_in[17];

  float* out = (float*)d_out;
  char* ws = (char*)d_ws;
  const size_t MB = 1048576;
  float2* stats = (float2*)ws;
  float2* part  = (float2*)(ws + (64 << 10));
  short*  WrS   = (short*)(ws + (256 << 10));
  const short8* Wr = (const short8*)WrS;
  bf16* P0 = (bf16*)(ws + 10 * MB);
  bf16* P1 = (bf16*)(ws + 27 * MB);
  bf16* P2 = (bf16*)(ws + 44 * MB);
  bf16* X1 = P0;
  bf16* X2 = (bf16*)d_out;
  const float2* nost = (const float2*)nullptr;

  // ---- stage 1: conv1a -> conv1b -> stats (apply fused into conv2a) ----
  conv1a_k<<<dim3(256, 4, 4), 256, 0, stream>>>(color, X1, w1a, b1a);
  repack_k<<<36, 256, 0, stream>>>(w1b, WrS, 64, 64);
  conv_mfma_k<16, 16, 0><<<dim3(256, 1, 4), 256, 0, stream>>>(
      X1, X2, Wr, b1b, nost, 256, 256, 256, 64, 64, 16);
  inorm_stats1_k<<<dim3(64, 4), 256, 0, stream>>>(X2, part, 65536, 64, 4, 64);
  inorm_stats2_k<<<dim3(1, 4), 256, 0, stream>>>(part, stats, 65536, 64, 64, 4);

  // ---- stage 2: conv2a (raw X2 + stats) -> conv2b -> pad apply ----
  repack_k<<<72, 256, 0, stream>>>(w2a, WrS, 64, 128);
  conv_mfma_k<16, 16, 1><<<dim3(64, 2, 4), 256, 0, stream>>>(
      X2, P0, Wr, b2a, stats, 256, 128, 128, 64, 128, 8);
  repack_k<<<144, 256, 0, stream>>>(w2b, WrS, 128, 128);
  conv_mfma_k<16, 16, 0><<<dim3(64, 2, 4), 256, 0, stream>>>(
      P0, P1, Wr, b2b, nost, 128, 128, 128, 128, 128, 8);
  inorm_stats1_k<<<dim3(64, 4), 256, 0, stream>>>(P1, part, 16384, 128, 4, 64);
  inorm_stats2_k<<<dim3(2, 4), 256, 0, stream>>>(part, stats, 16384, 128, 64, 4);
  inorm_apply_pad_k<<<dim3(128, 2, 4), 256, 0, stream>>>(P1, stats, P2);

  // ---- correlation (MFMA), split into 2 half-batch dispatches ----
  corr_mfma_k<<<dim3(128 * 8, 1, 2), 256, 0, stream>>>(corr, P2, out, P0, 0);
  corr_mfma_k<<<dim3(128 * 8, 1, 2), 256, 0, stream>>>(corr, P2, out, P0, 2);

  // ---- stage 3: conv3a -> conv3b -> stats; apply writes f32 only ----
  repack_k<<<288, 256, 0, stream>>>(w3a, WrS, 128, 256);
  conv_mfma_k<16, 16, 1><<<dim3(16, 4, 4), 256, 0, stream>>>(
      P0, P1, Wr, b3a, nost, 128, 64, 64, 128, 256, 4);
  repack_k<<<576, 256, 0, stream>>>(w3b, WrS, 256, 256);
  conv_mfma_k<16, 16, 0><<<dim3(16, 4, 4), 256, 0, stream>>>(
      P1, P2, Wr, b3b, nost, 64, 64, 64, 256, 256, 4);
  inorm_stats1_k<<<dim3(32, 4), 256, 0, stream>>>(P2, part, 4096, 256, 4, 32);
  inorm_stats2_k<<<dim3(4, 4), 256, 0, stream>>>(part, stats, 4096, 256, 32, 4);
  inorm_apply_k<<<dim3(1024, 4, 4), 256, 0, stream>>>(
      P2, stats, 4096, 256, (bf16*)nullptr, out + 8388608);

  // ---- stage 4: conv4a (raw P2 + stats) -> conv4b -> inorm ----
  repack_k<<<1152, 256, 0, stream>>>(w4a, WrS, 256, 512);
  conv_mfma_k<8, 16, 1><<<dim3(8, 8, 4), 256, 0, stream>>>(
      P2, P1, Wr, b4a, stats, 64, 32, 32, 256, 512, 2);
  repack_k<<<2304, 256, 0, stream>>>(w4b, WrS, 512, 512);
  conv_mfma_k<8, 16, 0><<<dim3(8, 8, 4), 256, 0, stream>>>(
      P1, P2, Wr, b4b, nost, 32, 32, 32, 512, 512, 2);
  inorm_stats1_k<<<dim3(32, 4), 256, 0, stream>>>(P2, part, 1024, 512, 4, 32);
  inorm_stats2_k<<<dim3(8, 4), 256, 0, stream>>>(part, stats, 1024, 512, 32, 4);
  inorm_apply_k<<<dim3(256, 8, 4), 256, 0, stream>>>(
      P2, stats, 1024, 512, (bf16*)nullptr, out + 12582912);
}

// Round 19
// 487.655 us; speedup vs baseline: 1.5410x; 1.0182x over previous
//
#include <hip/hip_runtime.h>
#include <hip/hip_bf16.h>

typedef __hip_bfloat16 bf16;
typedef __attribute__((ext_vector_type(8))) short short8;
typedef __attribute__((ext_vector_type(4))) float f32x4;

__device__ __forceinline__ float b2f(bf16 v) { return __bfloat162float(v); }
__device__ __forceinline__ bf16 f2b(float v) { return __float2bfloat16(v); }
__device__ __forceinline__ short fbits(float v) {
  bf16 h = f2b(v); return *reinterpret_cast<short*>(&h);
}
__device__ __forceinline__ float sb2f(short s) {
  return b2f(*reinterpret_cast<bf16*>(&s));
}
// bijective XCD swizzle (m204): contiguous grid chunk per XCD
__device__ __forceinline__ int xcd_swz(int bid, int nwg) {
  int q = nwg >> 3, r = nwg & 7;
  int xcd = bid & 7, idx = bid >> 3;
  return (xcd < r ? xcd * (q + 1) : r * (q + 1) + (xcd - r) * q) + idx;
}

// ---------------------------------------------------------------------------
// Weight repack: w[co][ci][ky][kx] f32  ->  B-fragment order, hi/lo bf16 split.
// ---------------------------------------------------------------------------
__global__ __launch_bounds__(256) void repack_k(
    const float* __restrict__ w, short* __restrict__ Wr, int Cin, int Cout)
{
  const int nkc = Cin >> 5, ncof = Cout >> 4;
  const size_t gid = (size_t)blockIdx.x * 256 + threadIdx.x;
  const int lane = gid & 63;
  size_t r = gid >> 6;
  const int tap = r % 9; r /= 9;
  const int kcc = r % nkc; r /= nkc;
  const int cof = r % ncof;
  const int hl = r / ncof;
  const int co = cof * 16 + (lane & 15);
  short8 v;
#pragma unroll
  for (int j = 0; j < 8; ++j) {
    int ci = kcc * 32 + ((lane >> 4) * 8 + j);
    float wv = w[((size_t)co * Cin + ci) * 9 + tap];
    bf16 hi = f2b(wv);
    v[j] = hl ? fbits(wv - b2f(hi)) : *reinterpret_cast<short*>(&hi);
  }
  *reinterpret_cast<short8*>(Wr + gid * 8) = v;
}

// ---------------------------------------------------------------------------
// MFMA implicit-GEMM 3x3 conv, per-layer tile FM = R*CX/32.
// 1D grid, COG-MAJOR ordering + XCD swizzle: each XCD owns a contiguous
// cog range -> weight slices L2-filled by 1-2 XCDs (r18: FETCH 39.5MB from
// ~8-XCD weight refetch at 10% occupancy). Block count >= 512 every layer.
// Optional `stats` fused during staging (bit-exact inorm apply).
// S=1: conv on the SUBSAMPLED image (subsample-then-pad-conv).
// ---------------------------------------------------------------------------
template<int R, int CX, int S>
__global__ __launch_bounds__(256) void conv_mfma_k(
    const bf16* __restrict__ src, bf16* __restrict__ dst,
    const short8* __restrict__ Wr, const float* __restrict__ bias,
    const float2* __restrict__ stats,
    int Win, int Hout, int Wout, int Cin, int Cout, int XT)
{
  constexpr int ROWS = R + 2;
  constexpr int COLS = CX + 2;
  constexpr int NGR = ROWS * 4 * COLS;
  constexpr int FM = (R * CX) / 32;
  __shared__ short8 a_s[NGR];

  // cog-major flat decomposition (b inside, px fastest)
  const int ytn = Hout / R;
  const int nxy = XT * ytn;
  const int wg = xcd_swz(blockIdx.x, gridDim.x);
  const int cog = wg / (4 * nxy);
  const int rem = wg - cog * (4 * nxy);
  const int b = rem / nxy;
  const int pxb = rem - b * nxy;
  const int xt = pxb % XT, yt = pxb / XT;
  const int x0 = xt * CX, y0 = yt * R;

  const int tid = threadIdx.x, lane = tid & 63, wid = tid >> 6;
  const int wm = wid & 1, wn = wid >> 1;
  const int nkc = Cin >> 5;
  const int ncof = Cout >> 4;
  const int l15 = lane & 15, lg = lane >> 4;

  f32x4 acc[FM][2] = {};

  int arow[FM], acolb[FM];
#pragma unroll
  for (int fm = 0; fm < FM; ++fm) {
    int p = wm * (R * CX / 2) + fm * 16 + l15;
    arow[fm] = p / CX;
    acolb[fm] = p % CX;
  }

  auto bload = [&](int hl, int fn, int kcc, int tap) -> short8 {
    int cof = cog * 4 + wn * 2 + fn;
    return Wr[((((size_t)hl * ncof + cof) * nkc + kcc) * 9 + tap) * 64 + lane];
  };

  short8 bc[2][2], bn_[2][2];
  bc[0][0] = bload(0, 0, 0, 0); bc[0][1] = bload(0, 1, 0, 0);
  bc[1][0] = bload(1, 0, 0, 0); bc[1][1] = bload(1, 1, 0, 0);

  for (int kc = 0; kc < nkc; ++kc) {
    __syncthreads();
    for (int idx = tid; idx < NGR; idx += 256) {
      int g = idx & 3, cix = idx >> 2;
      int col = cix % COLS, row = cix / COLS;
      int sy = y0 + row - 1;
      int sx = x0 + col - 1;
      short8 v = {};
      if (sy >= 0 && sy < Hout && sx >= 0 && sx < Wout) {
        int ry = S ? 2 * sy : sy, rx = S ? 2 * sx : sx;
        v = *reinterpret_cast<const short8*>(
            reinterpret_cast<const short*>(src) +
            (((size_t)b * (S ? 2 * Hout : Hout) + ry) * Win + rx) * Cin +
            kc * 32 + g * 8);
        if (stats) {                     // fused inorm apply (bit-exact)
          const float2* st = stats + (size_t)b * Cin + kc * 32 + g * 8;
#pragma unroll
          for (int j = 0; j < 8; ++j)
            v[j] = fbits((sb2f(v[j]) - st[j].x) * st[j].y);
        }
      }
      a_s[(row * 4 + g) * COLS + col] = v;
    }
    __syncthreads();

#pragma unroll
    for (int tap = 0; tap < 9; ++tap) {
      const int dy = tap / 3, dx = tap % 3;
      int nt = tap + 1, nk = kc;
      if (nt == 9) { nt = 0; nk = (kc + 1 < nkc) ? kc + 1 : 0; }
      bn_[0][0] = bload(0, 0, nk, nt); bn_[0][1] = bload(0, 1, nk, nt);
      bn_[1][0] = bload(1, 0, nk, nt); bn_[1][1] = bload(1, 1, nk, nt);
#pragma unroll
      for (int fm = 0; fm < FM; ++fm) {
        short8 a = a_s[((arow[fm] + dy) * 4 + lg) * COLS + acolb[fm] + dx];
        acc[fm][0] = __builtin_amdgcn_mfma_f32_16x16x32_bf16(a, bc[0][0], acc[fm][0], 0, 0, 0);
        acc[fm][0] = __builtin_amdgcn_mfma_f32_16x16x32_bf16(a, bc[1][0], acc[fm][0], 0, 0, 0);
        acc[fm][1] = __builtin_amdgcn_mfma_f32_16x16x32_bf16(a, bc[0][1], acc[fm][1], 0, 0, 0);
        acc[fm][1] = __builtin_amdgcn_mfma_f32_16x16x32_bf16(a, bc[1][1], acc[fm][1], 0, 0, 0);
      }
      bc[0][0] = bn_[0][0]; bc[0][1] = bn_[0][1];
      bc[1][0] = bn_[1][0]; bc[1][1] = bn_[1][1];
    }
  }

#pragma unroll
  for (int fn = 0; fn < 2; ++fn) {
    int co = cog * 64 + wn * 32 + fn * 16 + l15;
    float bs = bias[co];
#pragma unroll
    for (int fm = 0; fm < FM; ++fm) {
#pragma unroll
      for (int j = 0; j < 4; ++j) {
        int p = wm * (R * CX / 2) + fm * 16 + lg * 4 + j;
        int r = p / CX, x = p % CX;
        float v = fmaxf(acc[fm][fn][j] + bs, 0.f);
        dst[((size_t)(b * Hout + y0 + r) * Wout + x0 + x) * Cout + co] = f2b(v);
      }
    }
  }
}

// ---------------------------------------------------------------------------
// conv1a: Cin=2 VALU direct conv. NCHW f32 color (subsample-then-conv),
// NHWC bf16 out, bias+ReLU.
// ---------------------------------------------------------------------------
__global__ __launch_bounds__(256) void conv1a_k(
    const float* __restrict__ src, bf16* __restrict__ dst,
    const float* __restrict__ w, const float* __restrict__ bias)
{
  const int b = blockIdx.z, cog = blockIdx.y;
  const int ty0 = (blockIdx.x / 16) * 16, tx0 = (blockIdx.x % 16) * 16;
  const int tid = threadIdx.x, tx = tid & 15, ty = tid >> 4;

  __shared__ float in_s[2][18][18];
  __shared__ __align__(16) float w_s[2][3][3][16];

  for (int idx = tid; idx < 2 * 324; idx += 256) {
    int ci = idx / 324, r = idx - ci * 324;
    int iy = r / 18, ix = r - iy * 18;
    int gy = ty0 + iy - 1, gx = tx0 + ix - 1;
    float v = 0.f;
    if (gy >= 0 && gy < 256 && gx >= 0 && gx < 256)
      v = src[((size_t)(b * 2 + ci) * 512 + 2 * gy) * 512 + 2 * gx];
    in_s[ci][iy][ix] = v;
  }
  for (int idx = tid; idx < 2 * 144; idx += 256) {
    int co = idx & 15, r = idx >> 4;
    int ci = r / 9, k = r - ci * 9;
    w_s[ci][k / 3][k % 3][co] = w[(size_t)((cog * 16 + co) * 2 + ci) * 9 + k];
  }
  __syncthreads();

  float acc[16];
#pragma unroll
  for (int i = 0; i < 16; ++i) acc[i] = 0.f;
  for (int ci = 0; ci < 2; ++ci)
#pragma unroll
    for (int dy = 0; dy < 3; ++dy)
#pragma unroll
      for (int dx = 0; dx < 3; ++dx) {
        float v = in_s[ci][ty + dy][tx + dx];
        const float4* wv = (const float4*)(&w_s[ci][dy][dx][0]);
        float4 w0 = wv[0], w1 = wv[1], w2 = wv[2], w3 = wv[3];
        acc[0] = fmaf(v, w0.x, acc[0]);   acc[1] = fmaf(v, w0.y, acc[1]);
        acc[2] = fmaf(v, w0.z, acc[2]);   acc[3] = fmaf(v, w0.w, acc[3]);
        acc[4] = fmaf(v, w1.x, acc[4]);   acc[5] = fmaf(v, w1.y, acc[5]);
        acc[6] = fmaf(v, w1.z, acc[6]);   acc[7] = fmaf(v, w1.w, acc[7]);
        acc[8] = fmaf(v, w2.x, acc[8]);   acc[9] = fmaf(v, w2.y, acc[9]);
        acc[10] = fmaf(v, w2.z, acc[10]); acc[11] = fmaf(v, w2.w, acc[11]);
        acc[12] = fmaf(v, w3.x, acc[12]); acc[13] = fmaf(v, w3.y, acc[13]);
        acc[14] = fmaf(v, w3.z, acc[14]); acc[15] = fmaf(v, w3.w, acc[15]);
      }

  const int gy = ty0 + ty, gx = tx0 + tx;
  short8 s0, s1;
#pragma unroll
  for (int j = 0; j < 8; ++j) {
    s0[j] = fbits(fmaxf(acc[j] + bias[cog * 16 + j], 0.f));
    s1[j] = fbits(fmaxf(acc[8 + j] + bias[cog * 16 + 8 + j], 0.f));
  }
  short8* dp = reinterpret_cast<short8*>(
      reinterpret_cast<short*>(dst) + (((size_t)(b * 256 + gy) * 256 + gx) * 64 + cog * 16));
  dp[0] = s0; dp[1] = s1;
}

// ---------------------------------------------------------------------------
// InstanceNorm stats, 2-level (r17 vectorized stats1).
// ---------------------------------------------------------------------------
__global__ __launch_bounds__(256) void inorm_stats1_k(
    const bf16* __restrict__ x, float2* __restrict__ part,
    int HW, int C, int nb, int PC)
{
  const int b = blockIdx.y, pc = blockIdx.x;
  const int NC8 = C >> 3;
  const int pgc = 256 / NC8;
  const int c8 = (threadIdx.x % NC8) * 8;
  const int pg = threadIdx.x / NC8;
  const int chunk = HW / PC;
  const int p0 = pc * chunk;

  float s[8] = {}, ss[8] = {};
  for (int p = p0 + pg; p < p0 + chunk; p += pgc) {
    short8 v = *reinterpret_cast<const short8*>(
        reinterpret_cast<const short*>(x) + ((size_t)b * HW + p) * C + c8);
#pragma unroll
    for (int j = 0; j < 8; ++j) {
      float f = sb2f(v[j]);
      s[j] += f; ss[j] += f * f;
    }
  }
  __shared__ float sh[2][2048];
#pragma unroll
  for (int j = 0; j < 8; ++j) {
    sh[0][pg * C + c8 + j] = s[j];
    sh[1][pg * C + c8 + j] = ss[j];
  }
  __syncthreads();
  for (int c = threadIdx.x; c < C; c += 256) {
    float as = 0.f, aq = 0.f;
    for (int g = 0; g < pgc; ++g) { as += sh[0][g * C + c]; aq += sh[1][g * C + c]; }
    part[((size_t)pc * nb + b) * C + c] = make_float2(as, aq);
  }
}

__global__ __launch_bounds__(256) void inorm_stats2_k(
    const float2* __restrict__ part, float2* __restrict__ stats,
    int HW, int C, int PC, int nb)
{
  const int b = blockIdx.y, cg = blockIdx.x;
  const int c = threadIdx.x & 63, i = threadIdx.x >> 6;
  float s = 0.f, ss = 0.f;
  for (int pc = i; pc < PC; pc += 4) {
    float2 v = part[((size_t)pc * nb + b) * C + cg * 64 + c];
    s += v.x; ss += v.y;
  }
  __shared__ float sh[2][4][64];
  sh[0][i][c] = s; sh[1][i][c] = ss;
  __syncthreads();
  if (threadIdx.x < 64) {
    int cc = threadIdx.x;
    float s4 = sh[0][0][cc] + sh[0][1][cc] + sh[0][2][cc] + sh[0][3][cc];
    float q4 = sh[1][0][cc] + sh[1][1][cc] + sh[1][2][cc] + sh[1][3][cc];
    float m = s4 / (float)HW;
    float var = q4 / (float)HW - m * m;
    stats[(size_t)b * C + cg * 64 + cc] = make_float2(m, rsqrtf(var + 1e-5f));
  }
}

// generic apply: NHWC bf16 -> {NHWC bf16, NCHW f32} dests
__global__ __launch_bounds__(256) void inorm_apply_k(
    const bf16* __restrict__ x, const float2* __restrict__ stats, int HW, int C,
    bf16* __restrict__ dnhwc, float* __restrict__ fnchw)
{
  const int b = blockIdx.z, cg = blockIdx.y;
  const int c = cg * 64 + (threadIdx.x & 63);
  const int p = blockIdx.x * 4 + (threadIdx.x >> 6);
  const float2 st = stats[(size_t)b * C + c];
  const size_t ia = ((size_t)b * HW + p) * C + c;
  const float v = (b2f(x[ia]) - st.x) * st.y;
  if (dnhwc) dnhwc[ia] = f2b(v);
  if (fnchw) fnchw[((size_t)(b * C + c)) * HW + p] = v;
}

// ---------------------------------------------------------------------------
// Stage-2 apply: NHWC bf16 -> x-padded NCHW bf16 [b][c][128][144]
// ---------------------------------------------------------------------------
__global__ __launch_bounds__(256) void inorm_apply_pad_k(
    const bf16* __restrict__ x, const float2* __restrict__ stats,
    bf16* __restrict__ pad)
{
  const int b = blockIdx.z, cg = blockIdx.y, yy = blockIdx.x;
  const int tid = threadIdx.x;
  __shared__ bf16 t_s[64][130];
  __shared__ float2 st_s[64];
  if (tid < 64) st_s[tid] = stats[(size_t)b * 128 + cg * 64 + tid];
  __syncthreads();

  const int c8 = (tid & 7) * 8, px0 = tid >> 3;
#pragma unroll
  for (int pass = 0; pass < 4; ++pass) {
    int px = pass * 32 + px0;
    short8 v = *reinterpret_cast<const short8*>(
        reinterpret_cast<const short*>(x) +
        ((size_t)(b * 16384 + yy * 128 + px) * 128 + cg * 64 + c8));
#pragma unroll
    for (int j = 0; j < 8; ++j) {
      float2 st = st_s[c8 + j];
      t_s[c8 + j][px] = f2b((sb2f(v[j]) - st.x) * st.y);
    }
  }
  __syncthreads();

  for (int idx = tid; idx < 64 * 18; idx += 256) {
    int c = idx / 18, g = idx - (idx / 18) * 18;
    short8 v;
#pragma unroll
    for (int j = 0; j < 8; ++j) {
      int xx = g * 8 + j - 6;
      xx = xx < 0 ? 0 : (xx > 127 ? 127 : xx);
      v[j] = *reinterpret_cast<short*>(&t_s[c][xx]);
    }
    *reinterpret_cast<short8*>(
        reinterpret_cast<short*>(pad) +
        ((size_t)(b * 128 + cg * 64 + c) * 128 + yy) * 144 + g * 8) = v;
  }
}

// ---------------------------------------------------------------------------
// Correlation via MFMA banded GEMM (r11 structure, b0 batch-split).
// ---------------------------------------------------------------------------
__global__ __launch_bounds__(256) void corr_mfma_k(
    const float* __restrict__ corr, const bf16* __restrict__ pad,
    float* __restrict__ outc, bf16* __restrict__ outn, int b0)
{
  __shared__ __align__(16) char smem[26 * 64 * 16];
  short8* a_lds = reinterpret_cast<short8*>(smem);
  float* out_s = reinterpret_cast<float*>(smem);

  const int b = b0 + blockIdx.z;
  const int wg = xcd_swz(blockIdx.x, gridDim.x);
  const int y = wg >> 3, xt = wg & 7;
  const int x0 = xt * 16;
  const int tid = threadIdx.x, lane = tid & 63, wid = tid >> 6;
  const int l15 = lane & 15, lg = lane >> 4;

  for (int idx = tid; idx < 26 * 64; idx += 256) {
    short8 z = {};
    a_lds[idx] = z;
  }
  __syncthreads();

  unsigned short* ah = reinterpret_cast<unsigned short*>(a_lds);
  for (int idx = tid; idx < 169 * 16; idx += 256) {
    int t = idx >> 4, m = idx & 15;
    int dy = t / 13, dx = t - dy * 13;
    float f = corr[((size_t)b * 169 + t) * 16384 + y * 128 + x0 + m];
    bf16 hi = f2b(f);
    unsigned short hb = *reinterpret_cast<unsigned short*>(&hi);
    unsigned short lb = (unsigned short)fbits(f - b2f(hi));
    int k = m + dx;
    int ent = dy * 64 + (k >> 3) * 16 + m;
    ah[ent * 8 + (k & 7)] = hb;
    ah[(13 * 64 + ent) * 8 + (k & 7)] = lb;
  }
  __syncthreads();

  const int cg0 = wid * 2;
  f32x4 acc0 = {}, acc1 = {};
  const short* pb = reinterpret_cast<const short*>(pad);

  for (int dy = 0; dy < 13; ++dy) {
    int rowc = y + dy - 6; rowc = rowc < 0 ? 0 : (rowc > 127 ? 127 : rowc);
    short8 bhi = a_lds[dy * 64 + lane];
    short8 blo = a_lds[(13 + dy) * 64 + lane];
    size_t base0 = ((size_t)(b * 128 + cg0 * 16 + l15) * 128 + rowc) * 144
                   + x0 + lg * 8;
    short8 a0 = *reinterpret_cast<const short8*>(pb + base0);
    short8 a1 = *reinterpret_cast<const short8*>(pb + base0 + (size_t)16 * 128 * 144);
    acc0 = __builtin_amdgcn_mfma_f32_16x16x32_bf16(a0, bhi, acc0, 0, 0, 0);
    acc1 = __builtin_amdgcn_mfma_f32_16x16x32_bf16(a1, bhi, acc1, 0, 0, 0);
    acc0 = __builtin_amdgcn_mfma_f32_16x16x32_bf16(a0, blo, acc0, 0, 0, 0);
    acc1 = __builtin_amdgcn_mfma_f32_16x16x32_bf16(a1, blo, acc1, 0, 0, 0);
  }
  __syncthreads();

#pragma unroll
  for (int cgi = 0; cgi < 2; ++cgi) {
    f32x4 a = cgi ? acc1 : acc0;
    float* dst4 = out_s + l15 * 132 + (cg0 + cgi) * 16 + lg * 4;
    *reinterpret_cast<f32x4*>(dst4) = a;
  }
  __syncthreads();

  {
    int px_ = tid >> 4, c8 = (tid & 15) * 8;
    const float* row = out_s + px_ * 132 + c8;
    short8 v;
#pragma unroll
    for (int j = 0; j < 8; ++j) v[j] = fbits(row[j]);
    *reinterpret_cast<short8*>(
        reinterpret_cast<short*>(outn) +
        ((size_t)(b * 16384 + y * 128 + x0 + px_)) * 128 + c8) = v;
  }
  {
    int ch = tid >> 1, pg = tid & 1;
    float v0[4], v1[4];
#pragma unroll
    for (int i = 0; i < 4; ++i) v0[i] = out_s[(pg * 8 + i) * 132 + ch];
#pragma unroll
    for (int i = 0; i < 4; ++i) v1[i] = out_s[(pg * 8 + 4 + i) * 132 + ch];
    float* dst = outc + ((size_t)(b * 128 + ch)) * 16384 + y * 128 + x0 + pg * 8;
    *reinterpret_cast<float4*>(dst) = make_float4(v0[0], v0[1], v0[2], v0[3]);
    *reinterpret_cast<float4*>(dst + 4) = make_float4(v1[0], v1[1], v1[2], v1[3]);
  }
}

// ---------------------------------------------------------------------------
// Workspace plan — BYTES, liveness-proven (round-5/6 table). Peak 62.9 MB.
// ---------------------------------------------------------------------------
extern "C" void kernel_launch(void* const* d_in, const int* in_sizes, int n_in,
                              void* d_out, int out_size, void* d_ws, size_t ws_size,
                              hipStream_t stream) {
  const float* color = (const float*)d_in[0];
  const float* corr  = (const float*)d_in[1];
  const float* w1a = (const float*)d_in[2];  const float* b1a = (const float*)d_in[3];
  const float* w1b = (const float*)d_in[4];  const float* b1b = (const float*)d_in[5];
  const float* w2a = (const float*)d_in[6];  const float* b2a = (const float*)d_in[7];
  const float* w2b = (const float*)d_in[8];  const float* b2b = (const float*)d_in[9];
  const float* w3a = (const float*)d_in[10]; const float* b3a = (const float*)d_in[11];
  const float* w3b = (const float*)d_in[12]; const float* b3b = (const float*)d_in[13];
  const float* w4a = (const float*)d_in[14]; const float* b4a = (const float*)d_in[15];
  const float* w4b = (const float*)d_in[16]; const float* b4b = (const float*)d_in[17];

  float* out = (float*)d_out;
  char* ws = (char*)d_ws;
  const size_t MB = 1048576;
  float2* stats = (float2*)ws;
  float2* part  = (float2*)(ws + (64 << 10));
  short*  WrS   = (short*)(ws + (256 << 10));
  const short8* Wr = (const short8*)WrS;
  bf16* P0 = (bf16*)(ws + 10 * MB);
  bf16* P1 = (bf16*)(ws + 27 * MB);
  bf16* P2 = (bf16*)(ws + 44 * MB);
  bf16* X1 = P0;
  bf16* X2 = (bf16*)d_out;
  const float2* nost = (const float2*)nullptr;

  // ---- stage 1: conv1a -> conv1b(FM8) -> stats (apply fused into conv2a) --
  conv1a_k<<<dim3(256, 4, 4), 256, 0, stream>>>(color, X1, w1a, b1a);
  repack_k<<<36, 256, 0, stream>>>(w1b, WrS, 64, 64);
  conv_mfma_k<16, 16, 0><<<1024, 256, 0, stream>>>(
      X1, X2, Wr, b1b, nost, 256, 256, 256, 64, 64, 16);
  inorm_stats1_k<<<dim3(64, 4), 256, 0, stream>>>(X2, part, 65536, 64, 4, 64);
  inorm_stats2_k<<<dim3(1, 4), 256, 0, stream>>>(part, stats, 65536, 64, 64, 4);

  // ---- stage 2: conv2a(FM8, raw X2+stats) -> conv2b(FM8) -> pad apply ----
  repack_k<<<72, 256, 0, stream>>>(w2a, WrS, 64, 128);
  conv_mfma_k<16, 16, 1><<<512, 256, 0, stream>>>(
      X2, P0, Wr, b2a, stats, 256, 128, 128, 64, 128, 8);
  repack_k<<<144, 256, 0, stream>>>(w2b, WrS, 128, 128);
  conv_mfma_k<16, 16, 0><<<512, 256, 0, stream>>>(
      P0, P1, Wr, b2b, nost, 128, 128, 128, 128, 128, 8);
  inorm_stats1_k<<<dim3(64, 4), 256, 0, stream>>>(P1, part, 16384, 128, 4, 64);
  inorm_stats2_k<<<dim3(2, 4), 256, 0, stream>>>(part, stats, 16384, 128, 64, 4);
  inorm_apply_pad_k<<<dim3(128, 2, 4), 256, 0, stream>>>(P1, stats, P2);

  // ---- correlation (MFMA), split into 2 half-batch dispatches ----
  corr_mfma_k<<<dim3(128 * 8, 1, 2), 256, 0, stream>>>(corr, P2, out, P0, 0);
  corr_mfma_k<<<dim3(128 * 8, 1, 2), 256, 0, stream>>>(corr, P2, out, P0, 2);

  // ---- stage 3: conv3a(FM4) -> conv3b(FM4) -> stats; apply f32 only ----
  repack_k<<<288, 256, 0, stream>>>(w3a, WrS, 128, 256);
  conv_mfma_k<8, 16, 1><<<512, 256, 0, stream>>>(
      P0, P1, Wr, b3a, nost, 128, 64, 64, 128, 256, 4);
  repack_k<<<576, 256, 0, stream>>>(w3b, WrS, 256, 256);
  conv_mfma_k<8, 16, 0><<<512, 256, 0, stream>>>(
      P1, P2, Wr, b3b, nost, 64, 64, 64, 256, 256, 4);
  inorm_stats1_k<<<dim3(32, 4), 256, 0, stream>>>(P2, part, 4096, 256, 4, 32);
  inorm_stats2_k<<<dim3(4, 4), 256, 0, stream>>>(part, stats, 4096, 256, 32, 4);
  inorm_apply_k<<<dim3(1024, 4, 4), 256, 0, stream>>>(
      P2, stats, 4096, 256, (bf16*)nullptr, out + 8388608);

  // ---- stage 4: conv4a(FM2, raw P2+stats) -> conv4b(FM2) -> inorm ----
  repack_k<<<1152, 256, 0, stream>>>(w4a, WrS, 256, 512);
  conv_mfma_k<4, 16, 1><<<512, 256, 0, stream>>>(
      P2, P1, Wr, b4a, stats, 64, 32, 32, 256, 512, 2);
  repack_k<<<2304, 256, 0, stream>>>(w4b, WrS, 512, 512);
  conv_mfma_k<4, 16, 0><<<512, 256, 0, stream>>>(
      P1, P2, Wr, b4b, nost, 32, 32, 32, 512, 512, 2);
  inorm_stats1_k<<<dim3(32, 4), 256, 0, stream>>>(P2, part, 1024, 512, 4, 32);
  inorm_stats2_k<<<dim3(8, 4), 256, 0, stream>>>(part, stats, 1024, 512, 32, 4);
  inorm_apply_k<<<dim3(256, 8, 4), 256, 0, stream>>>(
      P2, stats, 1024, 512, (bf16*)nullptr, out + 12582912);
}